// Round 10
// baseline (435.376 us; speedup 1.0000x reference)
//
#include <hip/hip_runtime.h>
#include <hip/hip_bf16.h>

#define F 128
#define NB 20
#define KP 32          // padded K for the edge-embedding MFMA
#define HSTRIDE 136
#define HROWS_STRIDE 140   // h-row LDS stride (280B): 4-way-max bank aliasing for b64

typedef __attribute__((ext_vector_type(8))) short short8;
typedef __attribute__((ext_vector_type(4))) short short4v;
typedef __attribute__((ext_vector_type(4))) float floatx4;

__device__ __forceinline__ float silu_f(float x) {
    return x * __builtin_amdgcn_rcpf(1.0f + __expf(-x));
}
__device__ __forceinline__ float bfs2f(short s) {
    unsigned int u = ((unsigned int)(unsigned short)s) << 16;
    float f; __builtin_memcpy(&f, &u, 4); return f;
}
__device__ __forceinline__ float lo_bf(unsigned int u) { return bfs2f((short)(u & 0xFFFF)); }
__device__ __forceinline__ float hi_bf(unsigned int u) { return bfs2f((short)(u >> 16)); }
__device__ __forceinline__ unsigned int pack_bf2(float d, float v) {
    __hip_bfloat16 db = __float2bfloat16(d), vb = __float2bfloat16(v);
    return (unsigned int)*(unsigned short*)&db
         | ((unsigned int)*(unsigned short*)&vb << 16);
}

// Cooperative weight staging: 128x128 bf16 matrix (32KB = 2048 x 16B chunks)
// global->reg, then reg->LDS fragment-major so MFMA aw reads are
// lane-contiguous ds_read_b128.  512-thread (4 chunks/thread) and
// 1024-thread (2 chunks/thread) variants.
__device__ __forceinline__ void stage_issue(const __hip_bfloat16* W, int t,
                                            short8 wreg[4]) {
#pragma unroll
    for (int r = 0; r < 4; ++r)
        wreg[r] = *(const short8*)(W + (size_t)(r * 512 + t) * 8);
}
__device__ __forceinline__ void stage_write_frag(__hip_bfloat16* wbuf, int t,
                                                 const short8 wreg[4]) {
#pragma unroll
    for (int r = 0; r < 4; ++r) {
        const int c0 = r * 512 + t;           // 16B chunk id in row-major W
        const int n = c0 >> 4, p = c0 & 15;   // row, 16B part (k = p*8..)
        const int ks = p >> 2;
        const int frag = ((n >> 6) * 4 + ((n >> 4) & 3)) * 4 + ks;
        const int lam = (((p & 3) * 16) + (n & 15)) ^ (ks << 1);
        *(short8*)(wbuf + (size_t)frag * 512 + lam * 8) = wreg[r];
    }
}
__device__ __forceinline__ void stage_issue_1k(const __hip_bfloat16* W, int t,
                                               short8 wreg[2]) {
#pragma unroll
    for (int r = 0; r < 2; ++r)
        wreg[r] = *(const short8*)(W + (size_t)(r * 1024 + t) * 8);
}
__device__ __forceinline__ void stage_write_frag_1k(__hip_bfloat16* wbuf, int t,
                                                    const short8 wreg[2]) {
#pragma unroll
    for (int r = 0; r < 2; ++r) {
        const int c0 = r * 1024 + t;
        const int n = c0 >> 4, p = c0 & 15;
        const int ks = p >> 2;
        const int frag = ((n >> 6) * 4 + ((n >> 4) & 3)) * 4 + ks;
        const int lam = (((p & 3) * 16) + (n & 15)) ^ (ks << 1);
        *(short8*)(wbuf + (size_t)frag * 512 + lam * 8) = wreg[r];
    }
}

// ---------------- single 2-layer MLP, LDS-staged weights (nmp) -------------
__global__ __launch_bounds__(512, 4) void mlp_staged_kernel(
    const __hip_bfloat16* __restrict__ X,
    const __hip_bfloat16* __restrict__ W1, const float* __restrict__ b1,
    const __hip_bfloat16* __restrict__ W2, const float* __restrict__ b2,
    __hip_bfloat16* __restrict__ Y)
{
    __shared__ __hip_bfloat16 hid[128 * HSTRIDE];
    __shared__ __hip_bfloat16 wbuf[32 * 512];
    const int t = threadIdx.x;
    const int wave = t >> 6;
    const int rg   = wave >> 1;
    const int wf   = wave & 1;
    const int lane = t & 63;
    const int quad = lane >> 4;
    const int l16  = lane & 15;
    const int eloc0 = rg * 32;
    const int e0 = blockIdx.x * 128 + eloc0;
    const int fbase = wf * 64;

    short8 bxk[4][2];
#pragma unroll
    for (int ks = 0; ks < 4; ++ks)
#pragma unroll
        for (int et = 0; et < 2; ++et)
            bxk[ks][et] = *(const short8*)(X + (size_t)(e0 + et * 16 + l16) * F
                                           + ks * 32 + quad * 8);

    short8 wreg[4];
    floatx4 acc[4][2];

    stage_issue(W1, t, wreg);
    stage_write_frag(wbuf, t, wreg);
    __syncthreads();

    // ===== layer 1 =====
    stage_issue(W2, t, wreg);     // prefetch under layer-1 compute
    __builtin_amdgcn_sched_barrier(0);
#pragma unroll
    for (int ft = 0; ft < 4; ++ft)
#pragma unroll
        for (int et = 0; et < 2; ++et)
            acc[ft][et] = (floatx4){0.f, 0.f, 0.f, 0.f};
#pragma unroll
    for (int ks = 0; ks < 4; ++ks) {
        short8 aw[4];
#pragma unroll
        for (int ft = 0; ft < 4; ++ft)
            aw[ft] = *(const short8*)(wbuf + ((wf * 4 + ft) * 4 + ks) * 512
                                      + ((lane ^ (ks << 1)) * 8));
#pragma unroll
        for (int ft = 0; ft < 4; ++ft)
#pragma unroll
            for (int et = 0; et < 2; ++et)
                acc[ft][et] = __builtin_amdgcn_mfma_f32_16x16x32_bf16(
                    aw[ft], bxk[ks][et], acc[ft][et], 0, 0, 0);
    }
#pragma unroll
    for (int ft = 0; ft < 4; ++ft) {
        const int feat = fbase + ft * 16 + quad * 4;
        const floatx4 bv = *(const floatx4*)(b1 + feat);
#pragma unroll
        for (int et = 0; et < 2; ++et) {
            const int el = eloc0 + et * 16 + l16;
            __align__(8) __hip_bfloat16 tmp[4];
#pragma unroll
            for (int r = 0; r < 4; ++r)
                tmp[r] = __float2bfloat16(silu_f(acc[ft][et][r] + bv[r]));
            *(short4v*)(hid + (size_t)el * HSTRIDE + feat) = *(const short4v*)tmp;
        }
    }
    __syncthreads();
    stage_write_frag(wbuf, t, wreg);    // W2 -> wbuf
    __syncthreads();

    // ===== layer 2 =====
#pragma unroll
    for (int ft = 0; ft < 4; ++ft)
#pragma unroll
        for (int et = 0; et < 2; ++et)
            acc[ft][et] = (floatx4){0.f, 0.f, 0.f, 0.f};
#pragma unroll
    for (int ks = 0; ks < 4; ++ks) {
        const int k0 = ks * 32 + quad * 8;
        short8 bh[2], aw[4];
#pragma unroll
        for (int et = 0; et < 2; ++et)
            bh[et] = *(const short8*)(hid + (size_t)(eloc0 + et * 16 + l16) * HSTRIDE + k0);
#pragma unroll
        for (int ft = 0; ft < 4; ++ft)
            aw[ft] = *(const short8*)(wbuf + ((wf * 4 + ft) * 4 + ks) * 512
                                      + ((lane ^ (ks << 1)) * 8));
#pragma unroll
        for (int ft = 0; ft < 4; ++ft)
#pragma unroll
            for (int et = 0; et < 2; ++et)
                acc[ft][et] = __builtin_amdgcn_mfma_f32_16x16x32_bf16(
                    aw[ft], bh[et], acc[ft][et], 0, 0, 0);
    }
#pragma unroll
    for (int ft = 0; ft < 4; ++ft) {
        const int feat = fbase + ft * 16 + quad * 4;
        const floatx4 bv = *(const floatx4*)(b2 + feat);
#pragma unroll
        for (int et = 0; et < 2; ++et) {
            const int e = e0 + et * 16 + l16;
            __align__(8) __hip_bfloat16 tmp[4];
#pragma unroll
            for (int r = 0; r < 4; ++r)
                tmp[r] = __float2bfloat16(acc[ft][et][r] + bv[r]);
            *(short4v*)(Y + (size_t)e * F + feat) = *(const short4v*)tmp;
        }
    }
}

// ---------------- merged dual MLP, 256 rows/block (edge + node) ------------
// 1024 threads = 16 waves = 8 row-groups x 2 feature-halves; 256 rows/block
// halves the per-row staging + barrier fixed cost at the same static
// residency (16 waves/CU, 1 block/CU, LDS 102.4KB of 160KB).
// Blocks < ntile_e run the edge problem (eq1+eq2), the rest node (eq3+upd).
// Q2e may alias Xe (block reads its X rows before writing Q2 rows).
__global__ __launch_bounds__(1024, 4) void dual_mlp2_kernel(
    const __hip_bfloat16* Xe,
    const __hip_bfloat16* __restrict__ W1a_e, const float* __restrict__ b1a_e,
    const __hip_bfloat16* __restrict__ W2a_e, const float* __restrict__ b2a_e,
    const __hip_bfloat16* __restrict__ W1b_e, const float* __restrict__ b1b_e,
    const __hip_bfloat16* __restrict__ W2b_e, const float* __restrict__ b2b_e,
    __hip_bfloat16* __restrict__ Q1e, __hip_bfloat16* Q2e, int ntile_e,
    const __hip_bfloat16* __restrict__ Xn,
    const __hip_bfloat16* __restrict__ W1a_n,
    const __hip_bfloat16* __restrict__ W2a_n,
    const __hip_bfloat16* __restrict__ W1b_n, const float* __restrict__ b1b_n,
    const __hip_bfloat16* __restrict__ W2b_n, const float* __restrict__ b2b_n,
    __hip_bfloat16* __restrict__ Q1n, float* __restrict__ Q2n)
{
    __shared__ __hip_bfloat16 hid[256 * HSTRIDE];   // 69,632 B
    __shared__ __hip_bfloat16 wbuf[32 * 512];       // 32,768 B (fragment-major)
    const bool nn = (int)blockIdx.x >= ntile_e;     // node instance?
    const int tile = nn ? ((int)blockIdx.x - ntile_e) : (int)blockIdx.x;
    const __hip_bfloat16* X   = nn ? Xn : Xe;
    const __hip_bfloat16* W1a = nn ? W1a_n : W1a_e;
    const __hip_bfloat16* W2a = nn ? W2a_n : W2a_e;
    const __hip_bfloat16* W1b = nn ? W1b_n : W1b_e;
    const __hip_bfloat16* W2b = nn ? W2b_n : W2b_e;
    const float* b1a = nn ? nullptr : b1a_e;
    const float* b2a = nn ? nullptr : b2a_e;
    const float* b1b = nn ? b1b_n : b1b_e;
    const float* b2b = nn ? b2b_n : b2b_e;

    const int t = threadIdx.x;
    const int wave = t >> 6;       // 0..15
    const int rg   = wave >> 1;    // row-group 0..7 (32 rows each)
    const int wf   = wave & 1;     // feature half (64 features each)
    const int lane = t & 63;
    const int quad = lane >> 4;
    const int l16  = lane & 15;
    const int eloc0 = rg * 32;
    const int e0 = tile * 256 + eloc0;
    const int fbase = wf * 64;

    short8 bxk[4][2];
#pragma unroll
    for (int ks = 0; ks < 4; ++ks)
#pragma unroll
        for (int et = 0; et < 2; ++et)
            bxk[ks][et] = *(const short8*)(X + (size_t)(e0 + et * 16 + l16) * F
                                           + ks * 32 + quad * 8);

    short8 wreg[2];
    floatx4 acc[4][2];

    stage_issue_1k(W1a, t, wreg);
    stage_write_frag_1k(wbuf, t, wreg);
    __syncthreads();

    // ===== layer A1 =====
    stage_issue_1k(W2a, t, wreg);
    __builtin_amdgcn_sched_barrier(0);
#pragma unroll
    for (int ft = 0; ft < 4; ++ft)
#pragma unroll
        for (int et = 0; et < 2; ++et)
            acc[ft][et] = (floatx4){0.f, 0.f, 0.f, 0.f};
#pragma unroll
    for (int ks = 0; ks < 4; ++ks) {
        short8 aw[4];
#pragma unroll
        for (int ft = 0; ft < 4; ++ft)
            aw[ft] = *(const short8*)(wbuf + ((wf * 4 + ft) * 4 + ks) * 512
                                      + ((lane ^ (ks << 1)) * 8));
#pragma unroll
        for (int ft = 0; ft < 4; ++ft)
#pragma unroll
            for (int et = 0; et < 2; ++et)
                acc[ft][et] = __builtin_amdgcn_mfma_f32_16x16x32_bf16(
                    aw[ft], bxk[ks][et], acc[ft][et], 0, 0, 0);
    }
#pragma unroll
    for (int ft = 0; ft < 4; ++ft) {
        const int feat = fbase + ft * 16 + quad * 4;
        floatx4 bv = (floatx4){0.f, 0.f, 0.f, 0.f};
        if (b1a) bv = *(const floatx4*)(b1a + feat);
#pragma unroll
        for (int et = 0; et < 2; ++et) {
            const int el = eloc0 + et * 16 + l16;
            __align__(8) __hip_bfloat16 tmp[4];
#pragma unroll
            for (int r = 0; r < 4; ++r)
                tmp[r] = __float2bfloat16(silu_f(acc[ft][et][r] + bv[r]));
            *(short4v*)(hid + (size_t)el * HSTRIDE + feat) = *(const short4v*)tmp;
        }
    }
    __syncthreads();
    stage_write_frag_1k(wbuf, t, wreg);    // W2a
    __syncthreads();

    // ===== layer A2 =====
    stage_issue_1k(W1b, t, wreg);
    __builtin_amdgcn_sched_barrier(0);
#pragma unroll
    for (int ft = 0; ft < 4; ++ft)
#pragma unroll
        for (int et = 0; et < 2; ++et)
            acc[ft][et] = (floatx4){0.f, 0.f, 0.f, 0.f};
#pragma unroll
    for (int ks = 0; ks < 4; ++ks) {
        const int k0 = ks * 32 + quad * 8;
        short8 bh[2], aw[4];
#pragma unroll
        for (int et = 0; et < 2; ++et)
            bh[et] = *(const short8*)(hid + (size_t)(eloc0 + et * 16 + l16) * HSTRIDE + k0);
#pragma unroll
        for (int ft = 0; ft < 4; ++ft)
            aw[ft] = *(const short8*)(wbuf + ((wf * 4 + ft) * 4 + ks) * 512
                                      + ((lane ^ (ks << 1)) * 8));
#pragma unroll
        for (int ft = 0; ft < 4; ++ft)
#pragma unroll
            for (int et = 0; et < 2; ++et)
                acc[ft][et] = __builtin_amdgcn_mfma_f32_16x16x32_bf16(
                    aw[ft], bh[et], acc[ft][et], 0, 0, 0);
    }
#pragma unroll
    for (int ft = 0; ft < 4; ++ft) {
        const int feat = fbase + ft * 16 + quad * 4;
        floatx4 bv = (floatx4){0.f, 0.f, 0.f, 0.f};
        if (b2a) bv = *(const floatx4*)(b2a + feat);
#pragma unroll
        for (int et = 0; et < 2; ++et) {
            const int e = e0 + et * 16 + l16;
            __align__(8) __hip_bfloat16 tmp[4];
#pragma unroll
            for (int r = 0; r < 4; ++r)
                tmp[r] = __float2bfloat16(acc[ft][et][r] + bv[r]);
            *(short4v*)((nn ? Q1n : Q1e) + (size_t)e * F + feat) = *(const short4v*)tmp;
        }
    }
    __syncthreads();
    stage_write_frag_1k(wbuf, t, wreg);    // W1b
    __syncthreads();

    // ===== layer B1 =====
    stage_issue_1k(W2b, t, wreg);
    __builtin_amdgcn_sched_barrier(0);
#pragma unroll
    for (int ft = 0; ft < 4; ++ft)
#pragma unroll
        for (int et = 0; et < 2; ++et)
            acc[ft][et] = (floatx4){0.f, 0.f, 0.f, 0.f};
#pragma unroll
    for (int ks = 0; ks < 4; ++ks) {
        short8 aw[4];
#pragma unroll
        for (int ft = 0; ft < 4; ++ft)
            aw[ft] = *(const short8*)(wbuf + ((wf * 4 + ft) * 4 + ks) * 512
                                      + ((lane ^ (ks << 1)) * 8));
#pragma unroll
        for (int ft = 0; ft < 4; ++ft)
#pragma unroll
            for (int et = 0; et < 2; ++et)
                acc[ft][et] = __builtin_amdgcn_mfma_f32_16x16x32_bf16(
                    aw[ft], bxk[ks][et], acc[ft][et], 0, 0, 0);
    }
#pragma unroll
    for (int ft = 0; ft < 4; ++ft) {
        const int feat = fbase + ft * 16 + quad * 4;
        floatx4 bv = (floatx4){0.f, 0.f, 0.f, 0.f};
        if (b1b) bv = *(const floatx4*)(b1b + feat);
#pragma unroll
        for (int et = 0; et < 2; ++et) {
            const int el = eloc0 + et * 16 + l16;
            __align__(8) __hip_bfloat16 tmp[4];
#pragma unroll
            for (int r = 0; r < 4; ++r)
                tmp[r] = __float2bfloat16(silu_f(acc[ft][et][r] + bv[r]));
            *(short4v*)(hid + (size_t)el * HSTRIDE + feat) = *(const short4v*)tmp;
        }
    }
    __syncthreads();
    stage_write_frag_1k(wbuf, t, wreg);    // W2b
    __syncthreads();

    // ===== layer B2 =====
#pragma unroll
    for (int ft = 0; ft < 4; ++ft)
#pragma unroll
        for (int et = 0; et < 2; ++et)
            acc[ft][et] = (floatx4){0.f, 0.f, 0.f, 0.f};
#pragma unroll
    for (int ks = 0; ks < 4; ++ks) {
        const int k0 = ks * 32 + quad * 8;
        short8 bh[2], aw[4];
#pragma unroll
        for (int et = 0; et < 2; ++et)
            bh[et] = *(const short8*)(hid + (size_t)(eloc0 + et * 16 + l16) * HSTRIDE + k0);
#pragma unroll
        for (int ft = 0; ft < 4; ++ft)
            aw[ft] = *(const short8*)(wbuf + ((wf * 4 + ft) * 4 + ks) * 512
                                      + ((lane ^ (ks << 1)) * 8));
#pragma unroll
        for (int ft = 0; ft < 4; ++ft)
#pragma unroll
            for (int et = 0; et < 2; ++et)
                acc[ft][et] = __builtin_amdgcn_mfma_f32_16x16x32_bf16(
                    aw[ft], bh[et], acc[ft][et], 0, 0, 0);
    }
#pragma unroll
    for (int ft = 0; ft < 4; ++ft) {
        const int feat = fbase + ft * 16 + quad * 4;
        floatx4 bv = (floatx4){0.f, 0.f, 0.f, 0.f};
        if (b2b) bv = *(const floatx4*)(b2b + feat);
#pragma unroll
        for (int et = 0; et < 2; ++et) {
            const int e = e0 + et * 16 + l16;
            if (!nn) {
                __align__(8) __hip_bfloat16 tmp[4];
#pragma unroll
                for (int r = 0; r < 4; ++r)
                    tmp[r] = __float2bfloat16(acc[ft][et][r] + bv[r]);
                *(short4v*)(Q2e + (size_t)e * F + feat) = *(const short4v*)tmp;
            } else {
                floatx4 v;
#pragma unroll
                for (int r = 0; r < 4; ++r) v[r] = acc[ft][et][r] + bv[r];
                *(floatx4*)(Q2n + (size_t)e * F + feat) = v;
            }
        }
    }
}

// ---------------- edge invariant message: LDS-staged h rows -----------------
__global__ __launch_bounds__(256) void edge_inv_mfma_kernel(
    const __hip_bfloat16* __restrict__ dist_p,
    const __hip_bfloat16* __restrict__ empWt,   // [128 feat][32 k]
    const float* __restrict__ emp_b, const __hip_bfloat16* __restrict__ h,
    const int* __restrict__ src_p, const int* __restrict__ dst_p,
    __hip_bfloat16* __restrict__ Xbf, int E)
{
    __shared__ __hip_bfloat16 hrows[256 * HROWS_STRIDE];
    __shared__ int ridx[256];
    const int t = threadIdx.x;
    const int wave = t >> 6;
    const int lane = t & 63;
    const int quad = lane >> 4;
    const int l16  = lane & 15;
    const int e0b = blockIdx.x * 128;
    const int e0 = e0b + wave * 32;

    {
        const int le = (t < 128) ? t : (t - 128);
        const int e = e0b + le;
        const int idx = (e < E) ? ((t < 128) ? src_p[e] : dst_p[e]) : 0;
        ridx[t] = idx;
    }
    __syncthreads();

#pragma unroll
    for (int i = 0; i < 16; ++i) {
        const int idx = i * 256 + t;
        const int r = idx >> 4, part = idx & 15;
        const short8 v = *(const short8*)(h + (size_t)ridx[r] * F + part * 8);
        const short4v lo = __builtin_shufflevector(v, v, 0, 1, 2, 3);
        const short4v hi = __builtin_shufflevector(v, v, 4, 5, 6, 7);
        *(short4v*)(hrows + (size_t)r * HROWS_STRIDE + part * 8)     = lo;
        *(short4v*)(hrows + (size_t)r * HROWS_STRIDE + part * 8 + 4) = hi;
    }

    short8 bx[2], aw[8];
#pragma unroll
    for (int et = 0; et < 2; ++et)
        bx[et] = *(const short8*)(dist_p + (size_t)(e0 + et * 16 + l16) * KP + quad * 8);
#pragma unroll
    for (int ft = 0; ft < 8; ++ft)
        aw[ft] = *(const short8*)(empWt + (size_t)(ft * 16 + l16) * KP + quad * 8);

    floatx4 acc[8][2];
#pragma unroll
    for (int ft = 0; ft < 8; ++ft)
#pragma unroll
        for (int et = 0; et < 2; ++et)
            acc[ft][et] = __builtin_amdgcn_mfma_f32_16x16x32_bf16(
                aw[ft], bx[et], (floatx4){0.f, 0.f, 0.f, 0.f}, 0, 0, 0);

    __syncthreads();   // hrows complete

    int eidx[2];
#pragma unroll
    for (int et = 0; et < 2; ++et) eidx[et] = e0 + et * 16 + l16;

#pragma unroll
    for (int ft = 0; ft < 8; ++ft) {
        const int feat = ft * 16 + quad * 4;
        const floatx4 bv = *(const floatx4*)(emp_b + feat);
#pragma unroll
        for (int et = 0; et < 2; ++et) {
            const int le = wave * 32 + et * 16 + l16;      // local edge 0..127
            const short4v hs = *(const short4v*)(hrows + (size_t)le * HROWS_STRIDE + feat);
            const short4v hd = *(const short4v*)(hrows + (size_t)(128 + le) * HROWS_STRIDE + feat);
            const bool v = eidx[et] < E;
            __align__(8) __hip_bfloat16 tmp[4];
#pragma unroll
            for (int r = 0; r < 4; ++r) {
                const float m = v ? (acc[ft][et][r] + bv[r]) * bfs2f(hs[r]) * bfs2f(hd[r])
                                  : 0.0f;
                tmp[r] = __float2bfloat16(m);
            }
            *(short4v*)(Xbf + (size_t)eidx[et] * F + feat) = *(const short4v*)tmp;
        }
    }
}

// ---------------- merged prep: weights + empW + atom cast/pad + zero -------
__global__ void prep_all_kernel(
    const float* __restrict__ W0, const float* __restrict__ W1,
    const float* __restrict__ W2, const float* __restrict__ W3,
    const float* __restrict__ W4, const float* __restrict__ W5,
    const float* __restrict__ W6, const float* __restrict__ W7,
    const float* __restrict__ W8, const float* __restrict__ W9,
    const float* __restrict__ emp_W, const float* __restrict__ atom_node,
    __hip_bfloat16* __restrict__ Wt, __hip_bfloat16* __restrict__ empWt,
    __hip_bfloat16* __restrict__ atom_bf, __hip_bfloat16* __restrict__ atom_new_bf,
    int* __restrict__ counts, int nF, int nPadTot, int nPadTot2, int N)
{
    const int WTOT = 10 * F * F;      // 163840
    const int ETOT = F * KP;          // 4096
    const int S2 = WTOT + ETOT;
    const int S3 = S2 + nPadTot;                 // atom_bf region
    const int S4 = S3 + (nPadTot2 - nF);         // atom_new_bf pad region
    const int total = S4 + N;
    const int stride = gridDim.x * blockDim.x;
    for (int i = blockIdx.x * blockDim.x + threadIdx.x; i < total; i += stride) {
        if (i < WTOT) {
            const int w = i >> 14;
            const int idx = i & (F * F - 1);
            const int n = idx >> 7, k = idx & 127;
            const float* W = (w == 0) ? W0 : (w == 1) ? W1 : (w == 2) ? W2
                           : (w == 3) ? W3 : (w == 4) ? W4 : (w == 5) ? W5
                           : (w == 6) ? W6 : (w == 7) ? W7 : (w == 8) ? W8 : W9;
            Wt[i] = __float2bfloat16(W[k * F + n]);
        } else if (i < S2) {
            const int j = i - WTOT;
            const int n = j >> 5, k = j & (KP - 1);
            empWt[j] = __float2bfloat16(k < NB ? emp_W[k * F + n] : 0.0f);
        } else if (i < S3) {
            const int j = i - S2;
            atom_bf[j] = __float2bfloat16(j < nF ? atom_node[j] : 0.0f);
        } else if (i < S4) {
            atom_new_bf[(i - S3) + nF] = __float2bfloat16(0.0f);
        } else {
            counts[i - S4] = 0;
        }
    }
}

// ---------------- CSR build (edges grouped by src) ----------------

__global__ void csr_count_kernel(const int* __restrict__ src,
                                 int* __restrict__ counts, int E) {
    const int stride = gridDim.x * blockDim.x;
    for (int e = blockIdx.x * blockDim.x + threadIdx.x; e < E; e += stride)
        atomicAdd(&counts[src[e]], 1);
}

__global__ __launch_bounds__(1024) void csr_scan_kernel(
    const int* __restrict__ counts, int* __restrict__ offsets,
    int* __restrict__ cursor, int N)
{
    constexpr int T = 1024;
    const int t = threadIdx.x;
    const int per = (N + T - 1) / T;
    const int base = t * per;
    int lsum = 0;
    for (int i = 0; i < per; ++i) {
        int idx = base + i;
        if (idx < N) lsum += counts[idx];
    }
    __shared__ int s[T];
    s[t] = lsum;
    __syncthreads();
    for (int off = 1; off < T; off <<= 1) {
        int v = (t >= off) ? s[t - off] : 0;
        __syncthreads();
        s[t] += v;
        __syncthreads();
    }
    int run = s[t] - lsum;
    for (int i = 0; i < per; ++i) {
        int idx = base + i;
        if (idx < N) {
            offsets[idx] = run;
            cursor[idx] = run;
            run += counts[idx];
        }
    }
    if (t == T - 1) offsets[N] = run;
}

__global__ void csr_perm_kernel(const int* __restrict__ src,
                                const int* __restrict__ dst,
                                const float* __restrict__ disp_edge,
                                const float* __restrict__ dist_edge,
                                int* __restrict__ cursor,
                                int* __restrict__ src_p,
                                int* __restrict__ dst_p,
                                float* __restrict__ de_p,
                                __hip_bfloat16* __restrict__ dist_p, int E) {
    const int stride = gridDim.x * blockDim.x;
    for (int e = blockIdx.x * blockDim.x + threadIdx.x; e < E; e += stride) {
        const int s = src[e];
        const int pos = atomicAdd(&cursor[s], 1);
        src_p[pos] = s;
        dst_p[pos] = dst[e];
        de_p[3 * pos + 0] = disp_edge[3 * e + 0];
        de_p[3 * pos + 1] = disp_edge[3 * e + 1];
        de_p[3 * pos + 2] = disp_edge[3 * e + 2];
        __align__(16) __hip_bfloat16 tmp[KP];
#pragma unroll
        for (int k = 0; k < KP; ++k)
            tmp[k] = __float2bfloat16(k < NB ? dist_edge[(size_t)e * NB + k] : 0.0f);
#pragma unroll
        for (int q = 0; q < 4; ++q)
            *(short8*)(dist_p + (size_t)pos * KP + q * 8) = ((const short8*)tmp)[q];
    }
}

// ---------- per-node gathers: wave-per-node, 2 features/lane (4B+ loads) ----

__global__ __launch_bounds__(256) void gather_inv_kernel(
    const __hip_bfloat16* __restrict__ inv_msg, const int* __restrict__ offsets,
    const float* __restrict__ atom,
    float* __restrict__ atom_new, __hip_bfloat16* __restrict__ atom_new_bf, int N)
{
    const int n = blockIdx.x * 4 + (threadIdx.x >> 6);
    if (n >= N) return;
    const int f0 = (threadIdx.x & 63) * 2;
    const int p0 = offsets[n], p1 = offsets[n + 1];
    float a0 = 0.0f, a1 = 0.0f;
    for (int p = p0; p < p1; ++p) {
        const unsigned int u = *(const unsigned int*)(inv_msg + (size_t)p * F + f0);
        a0 += lo_bf(u);
        a1 += hi_bf(u);
    }
    const float2 av = *(const float2*)(atom + (size_t)n * F + f0);
    const float v0 = av.x + a0, v1 = av.y + a1;
    *(float2*)(atom_new + (size_t)n * F + f0) = make_float2(v0, v1);
    __hip_bfloat16 b0 = __float2bfloat16(v0), b1 = __float2bfloat16(v1);
    *(ushort2*)(atom_new_bf + (size_t)n * F + f0) =
        make_ushort2(*(unsigned short*)&b0, *(unsigned short*)&b1);
}

// eq1 gather + out_force + packed {bf16(disp_node), bf16(eq3i*agg1)} table
__global__ __launch_bounds__(256) void gather_eq1_kernel(
    const __hip_bfloat16* __restrict__ eqm, const float* __restrict__ de_p,
    const int* __restrict__ offsets,
    const float* __restrict__ force, const float* __restrict__ disp_node,
    const __hip_bfloat16* __restrict__ eq3i_bf,
    float* __restrict__ out_force, ushort2* __restrict__ pk, int N)
{
    const int n = blockIdx.x * 4 + (threadIdx.x >> 6);
    if (n >= N) return;
    const int f0 = (threadIdx.x & 63) * 2;
    const int p0 = offsets[n], p1 = offsets[n + 1];
    float a00 = 0.f, a01 = 0.f, a10 = 0.f, a11 = 0.f, a20 = 0.f, a21 = 0.f;
    for (int p = p0; p < p1; ++p) {
        const unsigned int u = *(const unsigned int*)(eqm + (size_t)p * F + f0);
        const float m0 = lo_bf(u), m1 = hi_bf(u);
        const float d0 = de_p[(size_t)p * 3 + 0];
        const float d1 = de_p[(size_t)p * 3 + 1];
        const float d2 = de_p[(size_t)p * 3 + 2];
        a00 = fmaf(m0, d0, a00); a01 = fmaf(m1, d0, a01);
        a10 = fmaf(m0, d1, a10); a11 = fmaf(m1, d1, a11);
        a20 = fmaf(m0, d2, a20); a21 = fmaf(m1, d2, a21);
    }
    const unsigned int ug = *(const unsigned int*)(eq3i_bf + (size_t)n * F + f0);
    const float g0 = lo_bf(ug), g1 = hi_bf(ug);
    const size_t b = (size_t)n * 3 * F + f0;

    float2 f;
    f = *(const float2*)(force + b);
    *(float2*)(out_force + b) = make_float2(f.x + a00, f.y + a01);
    f = *(const float2*)(force + b + F);
    *(float2*)(out_force + b + F) = make_float2(f.x + a10, f.y + a11);
    f = *(const float2*)(force + b + 2 * F);
    *(float2*)(out_force + b + 2 * F) = make_float2(f.x + a20, f.y + a21);

    float2 dn;
    dn = *(const float2*)(disp_node + b);
    *(uint2*)(pk + b) = make_uint2(pack_bf2(dn.x, g0 * a00), pack_bf2(dn.y, g1 * a01));
    dn = *(const float2*)(disp_node + b + F);
    *(uint2*)(pk + b + F) = make_uint2(pack_bf2(dn.x, g0 * a10), pack_bf2(dn.y, g1 * a11));
    dn = *(const float2*)(disp_node + b + 2 * F);
    *(uint2*)(pk + b + 2 * F) = make_uint2(pack_bf2(dn.x, g0 * a20), pack_bf2(dn.y, g1 * a21));
}

// merged eq2+eq3 gather + final update + LayerNorm
__global__ __launch_bounds__(256) void gather_eq23_ln_kernel(
    const __hip_bfloat16* __restrict__ eqm2, const ushort2* __restrict__ pk,
    const float* __restrict__ disp_node,
    const int* __restrict__ dst_p, const int* __restrict__ offsets,
    const float* __restrict__ atom_new, const float* __restrict__ upd,
    const float* __restrict__ out_force,
    const float* __restrict__ ln_g, const float* __restrict__ ln_b,
    float* __restrict__ out_disp, float* __restrict__ out_atom, int N)
{
    const int n = blockIdx.x * 4 + (threadIdx.x >> 6);
    if (n >= N) return;
    const int f0 = (threadIdx.x & 63) * 2;
    const int p0 = offsets[n], p1 = offsets[n + 1];
    float a00 = 0.f, a01 = 0.f, a10 = 0.f, a11 = 0.f, a20 = 0.f, a21 = 0.f;
    int d = (p0 < p1) ? dst_p[p0] : 0;
    for (int p = p0; p < p1; ++p) {
        const int dn = (p + 1 < p1) ? dst_p[p + 1] : 0;
        const unsigned int u = *(const unsigned int*)(eqm2 + (size_t)p * F + f0);
        const float m0 = lo_bf(u), m1 = hi_bf(u);
        const size_t pb = (size_t)d * 3 * F + f0;
        const uint2 c0 = *(const uint2*)(pk + pb);
        const uint2 c1 = *(const uint2*)(pk + pb + F);
        const uint2 c2 = *(const uint2*)(pk + pb + 2 * F);
        a00 += m0 * lo_bf(c0.x) + hi_bf(c0.x);
        a01 += m1 * lo_bf(c0.y) + hi_bf(c0.y);
        a10 += m0 * lo_bf(c1.x) + hi_bf(c1.x);
        a11 += m1 * lo_bf(c1.y) + hi_bf(c1.y);
        a20 += m0 * lo_bf(c2.x) + hi_bf(c2.x);
        a21 += m1 * lo_bf(c2.y) + hi_bf(c2.y);
        d = dn;
    }
    const size_t b = (size_t)n * 3 * F + f0;
    float2 dn2;
    dn2 = *(const float2*)(disp_node + b);
    const float2 od0 = make_float2(dn2.x + a00, dn2.y + a01);
    dn2 = *(const float2*)(disp_node + b + F);
    const float2 od1 = make_float2(dn2.x + a10, dn2.y + a11);
    dn2 = *(const float2*)(disp_node + b + 2 * F);
    const float2 od2 = make_float2(dn2.x + a20, dn2.y + a21);
    *(float2*)(out_disp + b)         = od0;
    *(float2*)(out_disp + b + F)     = od1;
    *(float2*)(out_disp + b + 2 * F) = od2;

    const float2 fo0 = *(const float2*)(out_force + b);
    const float2 fo1 = *(const float2*)(out_force + b + F);
    const float2 fo2 = *(const float2*)(out_force + b + 2 * F);
    const float s0 = -(fo0.x * od0.x + fo1.x * od1.x + fo2.x * od2.x);
    const float s1 = -(fo0.y * od0.y + fo1.y * od1.y + fo2.y * od2.y);

    const float2 an = *(const float2*)(atom_new + (size_t)n * F + f0);
    const float2 up = *(const float2*)(upd + (size_t)n * F + f0);
    const float y0 = an.x + up.x * s0;
    const float y1 = an.y + up.y * s1;

    float sy = y0 + y1, syy = y0 * y0 + y1 * y1;
#pragma unroll
    for (int m = 1; m < 64; m <<= 1) {
        sy  += __shfl_xor(sy, m);
        syy += __shfl_xor(syy, m);
    }
    const float mu = sy * (1.0f / F);
    float var = syy * (1.0f / F) - mu * mu;
    if (var < 0.0f) var = 0.0f;
    const float rstd = rsqrtf(var + 1e-5f);

    const float2 gg = *(const float2*)(ln_g + f0);
    const float2 bb = *(const float2*)(ln_b + f0);
    *(float2*)(out_atom + (size_t)n * F + f0) =
        make_float2((y0 - mu) * rstd * gg.x + bb.x,
                    (y1 - mu) * rstd * gg.y + bb.y);
}

extern "C" void kernel_launch(void* const* d_in, const int* in_sizes, int n_in,
                              void* d_out, int out_size, void* d_ws, size_t ws_size,
                              hipStream_t stream)
{
    const float* atom_node  = (const float*)d_in[0];
    const float* force_node = (const float*)d_in[1];
    const float* disp_node  = (const float*)d_in[2];
    const float* disp_edge  = (const float*)d_in[3];
    const float* dist_edge  = (const float*)d_in[4];
    const int*   edge_index = (const int*)d_in[5];
    const float* nmp_W1 = (const float*)d_in[6];
    const float* nmp_b1 = (const float*)d_in[7];
    const float* nmp_W2 = (const float*)d_in[8];
    const float* nmp_b2 = (const float*)d_in[9];
    const float* emp_W  = (const float*)d_in[10];
    const float* emp_b  = (const float*)d_in[11];
    const float* eq1_W1 = (const float*)d_in[12];
    const float* eq1_b1 = (const float*)d_in[13];
    const float* eq1_W2 = (const float*)d_in[14];
    const float* eq1_b2 = (const float*)d_in[15];
    const float* eq2_W1 = (const float*)d_in[16];
    const float* eq2_b1 = (const float*)d_in[17];
    const float* eq2_W2 = (const float*)d_in[18];
    const float* eq2_b2 = (const float*)d_in[19];
    const float* eq3_W1 = (const float*)d_in[20];
    const float* eq3_W2 = (const float*)d_in[21];
    const float* upd_W1 = (const float*)d_in[22];
    const float* upd_b1 = (const float*)d_in[23];
    const float* upd_W2 = (const float*)d_in[24];
    const float* upd_b2 = (const float*)d_in[25];
    const float* ln_g   = (const float*)d_in[26];
    const float* ln_b   = (const float*)d_in[27];

    const int N = in_sizes[0] / F;            // 10000
    const int E = in_sizes[4] / NB;           // 200000
    const int Mp   = ((E + 127) / 128) * 128;  // 200064 (edge_inv tiles)
    const int MpE  = ((E + 255) / 256) * 256;  // 200192 (dual 256-row tiles)
    const int Mp2  = ((N + 127) / 128) * 128;  // 10112 (mlp_staged tiles)
    const int Mp2b = ((N + 255) / 256) * 256;  // 10240 (dual node tiles)
    const int* src = edge_index;
    const int* dst = edge_index + E;
    const int nF = N * F, n3F = N * 3 * F;

    float* out_atom  = (float*)d_out;
    float* out_force = out_atom + (size_t)nF;
    float* out_disp  = out_force + (size_t)n3F;

    // ---- workspace layout ----
    char* p = (char*)d_ws;
    int* counts  = (int*)p;
    int* offsets = counts + N;
    int* cursor  = offsets + (N + 1);
    int* src_p   = cursor + N;
    int* dst_p   = src_p + E;
    size_t off = (size_t)(3 * N + 1 + 2 * E) * sizeof(int);
    off = (off + 63) & ~(size_t)63;
    float* de_p = (float*)(p + off); off += (size_t)3 * E * sizeof(float);
    off = (off + 63) & ~(size_t)63;
    __hip_bfloat16* dist_p = (__hip_bfloat16*)(p + off); off += (size_t)Mp * KP * 2;
    __hip_bfloat16* empWt  = (__hip_bfloat16*)(p + off); off += (size_t)F * KP * 2;

    __hip_bfloat16* h_bf        = (__hip_bfloat16*)(p + off); off += (size_t)Mp2 * F * 2;
    __hip_bfloat16* atom_bf     = (__hip_bfloat16*)(p + off); off += (size_t)Mp2 * F * 2;
    __hip_bfloat16* atom_new_bf = (__hip_bfloat16*)(p + off); off += (size_t)Mp2b * F * 2;
    __hip_bfloat16* eq3i_bf     = (__hip_bfloat16*)(p + off); off += (size_t)Mp2b * F * 2;
    off = (off + 63) & ~(size_t)63;
    float* atom_new = (float*)(p + off); off += (size_t)nF * 4;
    float* upd_f    = (float*)(p + off); off += (size_t)Mp2b * F * 4;
    ushort2* pk     = (ushort2*)(p + off); off += (size_t)n3F * sizeof(ushort2);
    off = (off + 63) & ~(size_t)63;
    __hip_bfloat16* Xbf = (__hip_bfloat16*)(p + off); off += (size_t)MpE * F * 2;
    __hip_bfloat16* Q1  = (__hip_bfloat16*)(p + off); off += (size_t)MpE * F * 2;
    __hip_bfloat16* Q2  = Xbf;   // alias: edge blocks read their X rows before writing Q2 rows
    __hip_bfloat16* Wt  = (__hip_bfloat16*)(p + off); // 10*F*F bf16
    __hip_bfloat16* Wt_eq1a = Wt + 0 * F * F;
    __hip_bfloat16* Wt_eq1b = Wt + 1 * F * F;
    __hip_bfloat16* Wt_eq2a = Wt + 2 * F * F;
    __hip_bfloat16* Wt_eq2b = Wt + 3 * F * F;
    __hip_bfloat16* Wt_nmpa = Wt + 4 * F * F;
    __hip_bfloat16* Wt_nmpb = Wt + 5 * F * F;
    __hip_bfloat16* Wt_eq3a = Wt + 6 * F * F;
    __hip_bfloat16* Wt_eq3b = Wt + 7 * F * F;
    __hip_bfloat16* Wt_upda = Wt + 8 * F * F;
    __hip_bfloat16* Wt_updb = Wt + 9 * F * F;

    // ---- merged prep (weights + empW + atom cast/pad + atom_new pad + zero counts)
    prep_all_kernel<<<1024, 256, 0, stream>>>(
        eq1_W1, eq1_W2, eq2_W1, eq2_W2, nmp_W1, nmp_W2, eq3_W1, eq3_W2,
        upd_W1, upd_W2, emp_W, atom_node,
        Wt, empWt, atom_bf, atom_new_bf, counts, nF, Mp2 * F, Mp2b * F, N);

    // ---- CSR build ----
    csr_count_kernel<<<256, 256, 0, stream>>>(src, counts, E);
    csr_scan_kernel<<<1, 1024, 0, stream>>>(counts, offsets, cursor, N);
    csr_perm_kernel<<<256, 256, 0, stream>>>(src, dst, disp_edge, dist_edge,
                                             cursor, src_p, dst_p, de_p, dist_p, E);

    // ---- h = mlp2(atom_node, nmp), LDS-staged weights ----
    mlp_staged_kernel<<<Mp2 / 128, 512, 0, stream>>>(
        atom_bf, Wt_nmpa, nmp_b1, Wt_nmpb, nmp_b2, h_bf);

    // ---- invariant message (MFMA + LDS-staged h products) + node aggregation
    edge_inv_mfma_kernel<<<Mp / 128, 256, 0, stream>>>(
        dist_p, empWt, emp_b, h_bf, src_p, dst_p, Xbf, E);
    gather_inv_kernel<<<(N + 3) / 4, 256, 0, stream>>>(Xbf, offsets, atom_node,
                                                       atom_new, atom_new_bf, N);

    // ---- merged dual MLPs, 256 rows/block: edge eq1+eq2 (782) + node (40) --
    {
        const int ntileE = MpE / 256;
        const int ntileN = Mp2b / 256;
        dual_mlp2_kernel<<<ntileE + ntileN, 1024, 0, stream>>>(
            Xbf, Wt_eq1a, eq1_b1, Wt_eq1b, eq1_b2,
            Wt_eq2a, eq2_b1, Wt_eq2b, eq2_b2, Q1, Q2, ntileE,
            atom_new_bf, Wt_eq3a, Wt_eq3b,
            Wt_upda, upd_b1, Wt_updb, upd_b2, eq3i_bf, upd_f);
    }

    // ---- gathers (+ fused LN in eq23) ----
    gather_eq1_kernel<<<(N + 3) / 4, 256, 0, stream>>>(
        Q1, de_p, offsets, force_node, disp_node, eq3i_bf, out_force, pk, N);
    gather_eq23_ln_kernel<<<(N + 3) / 4, 256, 0, stream>>>(
        Q2, pk, disp_node, dst_p, offsets, atom_new, upd_f, out_force,
        ln_g, ln_b, out_disp, out_atom, N);
}

// Round 11
// 412.720 us; speedup vs baseline: 1.0549x; 1.0549x over previous
//
#include <hip/hip_runtime.h>
#include <hip/hip_bf16.h>

#define F 128
#define NB 20
#define KP 32          // padded K for the edge-embedding MFMA
#define HSTRIDE 136
#define HROWS_STRIDE 140   // h-row LDS stride (280B): 4-way-max bank aliasing for b64

typedef __attribute__((ext_vector_type(8))) short short8;
typedef __attribute__((ext_vector_type(4))) short short4v;
typedef __attribute__((ext_vector_type(4))) float floatx4;

__device__ __forceinline__ float silu_f(float x) {
    return x * __builtin_amdgcn_rcpf(1.0f + __expf(-x));
}
__device__ __forceinline__ float bfs2f(short s) {
    unsigned int u = ((unsigned int)(unsigned short)s) << 16;
    float f; __builtin_memcpy(&f, &u, 4); return f;
}
__device__ __forceinline__ float lo_bf(unsigned int u) { return bfs2f((short)(u & 0xFFFF)); }
__device__ __forceinline__ float hi_bf(unsigned int u) { return bfs2f((short)(u >> 16)); }
__device__ __forceinline__ unsigned int pack_bf2(float d, float v) {
    __hip_bfloat16 db = __float2bfloat16(d), vb = __float2bfloat16(v);
    return (unsigned int)*(unsigned short*)&db
         | ((unsigned int)*(unsigned short*)&vb << 16);
}

// Cooperative weight staging (512 threads): 128x128 bf16 matrix global->reg.
__device__ __forceinline__ void stage_issue(const __hip_bfloat16* W, int t,
                                            short8 wreg[4]) {
#pragma unroll
    for (int r = 0; r < 4; ++r)
        wreg[r] = *(const short8*)(W + (size_t)(r * 512 + t) * 8);
}
// Fragment-major LDS layout: frag c = ((wf*4+ft)*4+ks) holds 64 lanes x 16B
// contiguous, so the MFMA aw ds_read_b128 is lane-contiguous.
// (Round-8 measured: conflict count is NOT on the critical path; layout kept.
//  Round-10 measured: 1024-thread/1-block-per-CU variant LOSES ~28% — the
//  2-blocks-per-CU barrier asynchrony is worth more than halved fixed cost.)
__device__ __forceinline__ void stage_write_frag(__hip_bfloat16* wbuf, int t,
                                                 const short8 wreg[4]) {
#pragma unroll
    for (int r = 0; r < 4; ++r) {
        const int c0 = r * 512 + t;           // 16B chunk id in row-major W
        const int n = c0 >> 4, p = c0 & 15;   // row, 16B part (k = p*8..)
        const int ks = p >> 2;
        const int frag = ((n >> 6) * 4 + ((n >> 4) & 3)) * 4 + ks;
        const int lam = (((p & 3) * 16) + (n & 15)) ^ (ks << 1);
        *(short8*)(wbuf + (size_t)frag * 512 + lam * 8) = wreg[r];
    }
}

// ---------------- single 2-layer MLP, LDS-staged weights (nmp) -------------
__global__ __launch_bounds__(512, 4) void mlp_staged_kernel(
    const __hip_bfloat16* __restrict__ X,
    const __hip_bfloat16* __restrict__ W1, const float* __restrict__ b1,
    const __hip_bfloat16* __restrict__ W2, const float* __restrict__ b2,
    __hip_bfloat16* __restrict__ Y)
{
    __shared__ __hip_bfloat16 hid[128 * HSTRIDE];
    __shared__ __hip_bfloat16 wbuf[32 * 512];
    const int t = threadIdx.x;
    const int wave = t >> 6;
    const int rg   = wave >> 1;
    const int wf   = wave & 1;
    const int lane = t & 63;
    const int quad = lane >> 4;
    const int l16  = lane & 15;
    const int eloc0 = rg * 32;
    const int e0 = blockIdx.x * 128 + eloc0;
    const int fbase = wf * 64;

    short8 bxk[4][2];
#pragma unroll
    for (int ks = 0; ks < 4; ++ks)
#pragma unroll
        for (int et = 0; et < 2; ++et)
            bxk[ks][et] = *(const short8*)(X + (size_t)(e0 + et * 16 + l16) * F
                                           + ks * 32 + quad * 8);

    short8 wreg[4];
    floatx4 acc[4][2];

    stage_issue(W1, t, wreg);
    stage_write_frag(wbuf, t, wreg);
    __syncthreads();

    // ===== layer 1 =====
    stage_issue(W2, t, wreg);     // prefetch under layer-1 compute
    __builtin_amdgcn_sched_barrier(0);
#pragma unroll
    for (int ft = 0; ft < 4; ++ft)
#pragma unroll
        for (int et = 0; et < 2; ++et)
            acc[ft][et] = (floatx4){0.f, 0.f, 0.f, 0.f};
#pragma unroll
    for (int ks = 0; ks < 4; ++ks) {
        short8 aw[4];
#pragma unroll
        for (int ft = 0; ft < 4; ++ft)
            aw[ft] = *(const short8*)(wbuf + ((wf * 4 + ft) * 4 + ks) * 512
                                      + ((lane ^ (ks << 1)) * 8));
#pragma unroll
        for (int ft = 0; ft < 4; ++ft)
#pragma unroll
            for (int et = 0; et < 2; ++et)
                acc[ft][et] = __builtin_amdgcn_mfma_f32_16x16x32_bf16(
                    aw[ft], bxk[ks][et], acc[ft][et], 0, 0, 0);
    }
#pragma unroll
    for (int ft = 0; ft < 4; ++ft) {
        const int feat = fbase + ft * 16 + quad * 4;
        const floatx4 bv = *(const floatx4*)(b1 + feat);
#pragma unroll
        for (int et = 0; et < 2; ++et) {
            const int el = eloc0 + et * 16 + l16;
            __align__(8) __hip_bfloat16 tmp[4];
#pragma unroll
            for (int r = 0; r < 4; ++r)
                tmp[r] = __float2bfloat16(silu_f(acc[ft][et][r] + bv[r]));
            *(short4v*)(hid + (size_t)el * HSTRIDE + feat) = *(const short4v*)tmp;
        }
    }
    __syncthreads();
    stage_write_frag(wbuf, t, wreg);    // W2 -> wbuf
    __syncthreads();

    // ===== layer 2 =====
#pragma unroll
    for (int ft = 0; ft < 4; ++ft)
#pragma unroll
        for (int et = 0; et < 2; ++et)
            acc[ft][et] = (floatx4){0.f, 0.f, 0.f, 0.f};
#pragma unroll
    for (int ks = 0; ks < 4; ++ks) {
        const int k0 = ks * 32 + quad * 8;
        short8 bh[2], aw[4];
#pragma unroll
        for (int et = 0; et < 2; ++et)
            bh[et] = *(const short8*)(hid + (size_t)(eloc0 + et * 16 + l16) * HSTRIDE + k0);
#pragma unroll
        for (int ft = 0; ft < 4; ++ft)
            aw[ft] = *(const short8*)(wbuf + ((wf * 4 + ft) * 4 + ks) * 512
                                      + ((lane ^ (ks << 1)) * 8));
#pragma unroll
        for (int ft = 0; ft < 4; ++ft)
#pragma unroll
            for (int et = 0; et < 2; ++et)
                acc[ft][et] = __builtin_amdgcn_mfma_f32_16x16x32_bf16(
                    aw[ft], bh[et], acc[ft][et], 0, 0, 0);
    }
#pragma unroll
    for (int ft = 0; ft < 4; ++ft) {
        const int feat = fbase + ft * 16 + quad * 4;
        const floatx4 bv = *(const floatx4*)(b2 + feat);
#pragma unroll
        for (int et = 0; et < 2; ++et) {
            const int e = e0 + et * 16 + l16;
            __align__(8) __hip_bfloat16 tmp[4];
#pragma unroll
            for (int r = 0; r < 4; ++r)
                tmp[r] = __float2bfloat16(acc[ft][et][r] + bv[r]);
            *(short4v*)(Y + (size_t)e * F + feat) = *(const short4v*)tmp;
        }
    }
}

// ---------------- merged dual MLP: edge (eq1+eq2) and node (eq3+upd) -------
// 512 threads = 8 waves = 4 row-groups x 2 feature-halves; 128 rows/block,
// 2 blocks/CU (the asynchronous-barrier sweet spot, round-10 verified).
__global__ __launch_bounds__(512, 4) void dual_mlp2_kernel(
    const __hip_bfloat16* Xe,
    const __hip_bfloat16* __restrict__ W1a_e, const float* __restrict__ b1a_e,
    const __hip_bfloat16* __restrict__ W2a_e, const float* __restrict__ b2a_e,
    const __hip_bfloat16* __restrict__ W1b_e, const float* __restrict__ b1b_e,
    const __hip_bfloat16* __restrict__ W2b_e, const float* __restrict__ b2b_e,
    __hip_bfloat16* __restrict__ Q1e, __hip_bfloat16* Q2e, int ntile_e,
    const __hip_bfloat16* __restrict__ Xn,
    const __hip_bfloat16* __restrict__ W1a_n,
    const __hip_bfloat16* __restrict__ W2a_n,
    const __hip_bfloat16* __restrict__ W1b_n, const float* __restrict__ b1b_n,
    const __hip_bfloat16* __restrict__ W2b_n, const float* __restrict__ b2b_n,
    __hip_bfloat16* __restrict__ Q1n, float* __restrict__ Q2n)
{
    __shared__ __hip_bfloat16 hid[128 * HSTRIDE];
    __shared__ __hip_bfloat16 wbuf[32 * 512];   // fragment-major, 32KB
    const bool nn = (int)blockIdx.x >= ntile_e;   // node instance?
    const int tile = nn ? ((int)blockIdx.x - ntile_e) : (int)blockIdx.x;
    const __hip_bfloat16* X   = nn ? Xn : Xe;
    const __hip_bfloat16* W1a = nn ? W1a_n : W1a_e;
    const __hip_bfloat16* W2a = nn ? W2a_n : W2a_e;
    const __hip_bfloat16* W1b = nn ? W1b_n : W1b_e;
    const __hip_bfloat16* W2b = nn ? W2b_n : W2b_e;
    const float* b1a = nn ? nullptr : b1a_e;
    const float* b2a = nn ? nullptr : b2a_e;
    const float* b1b = nn ? b1b_n : b1b_e;
    const float* b2b = nn ? b2b_n : b2b_e;

    const int t = threadIdx.x;
    const int wave = t >> 6;       // 0..7
    const int rg   = wave >> 1;    // row-group 0..3 (32 rows each)
    const int wf   = wave & 1;     // feature half (64 features each)
    const int lane = t & 63;
    const int quad = lane >> 4;
    const int l16  = lane & 15;
    const int eloc0 = rg * 32;
    const int e0 = tile * 128 + eloc0;
    const int fbase = wf * 64;

    short8 bxk[4][2];
#pragma unroll
    for (int ks = 0; ks < 4; ++ks)
#pragma unroll
        for (int et = 0; et < 2; ++et)
            bxk[ks][et] = *(const short8*)(X + (size_t)(e0 + et * 16 + l16) * F
                                           + ks * 32 + quad * 8);

    short8 wreg[4];
    floatx4 acc[4][2];

    stage_issue(W1a, t, wreg);
    stage_write_frag(wbuf, t, wreg);
    __syncthreads();

    // ===== layer A1 =====
    stage_issue(W2a, t, wreg);
    __builtin_amdgcn_sched_barrier(0);
#pragma unroll
    for (int ft = 0; ft < 4; ++ft)
#pragma unroll
        for (int et = 0; et < 2; ++et)
            acc[ft][et] = (floatx4){0.f, 0.f, 0.f, 0.f};
#pragma unroll
    for (int ks = 0; ks < 4; ++ks) {
        short8 aw[4];
#pragma unroll
        for (int ft = 0; ft < 4; ++ft)
            aw[ft] = *(const short8*)(wbuf + ((wf * 4 + ft) * 4 + ks) * 512
                                      + ((lane ^ (ks << 1)) * 8));
#pragma unroll
        for (int ft = 0; ft < 4; ++ft)
#pragma unroll
            for (int et = 0; et < 2; ++et)
                acc[ft][et] = __builtin_amdgcn_mfma_f32_16x16x32_bf16(
                    aw[ft], bxk[ks][et], acc[ft][et], 0, 0, 0);
    }
#pragma unroll
    for (int ft = 0; ft < 4; ++ft) {
        const int feat = fbase + ft * 16 + quad * 4;
        floatx4 bv = (floatx4){0.f, 0.f, 0.f, 0.f};
        if (b1a) bv = *(const floatx4*)(b1a + feat);
#pragma unroll
        for (int et = 0; et < 2; ++et) {
            const int el = eloc0 + et * 16 + l16;
            __align__(8) __hip_bfloat16 tmp[4];
#pragma unroll
            for (int r = 0; r < 4; ++r)
                tmp[r] = __float2bfloat16(silu_f(acc[ft][et][r] + bv[r]));
            *(short4v*)(hid + (size_t)el * HSTRIDE + feat) = *(const short4v*)tmp;
        }
    }
    __syncthreads();
    stage_write_frag(wbuf, t, wreg);    // W2a
    __syncthreads();

    // ===== layer A2 =====
    stage_issue(W1b, t, wreg);
    __builtin_amdgcn_sched_barrier(0);
#pragma unroll
    for (int ft = 0; ft < 4; ++ft)
#pragma unroll
        for (int et = 0; et < 2; ++et)
            acc[ft][et] = (floatx4){0.f, 0.f, 0.f, 0.f};
#pragma unroll
    for (int ks = 0; ks < 4; ++ks) {
        const int k0 = ks * 32 + quad * 8;
        short8 bh[2], aw[4];
#pragma unroll
        for (int et = 0; et < 2; ++et)
            bh[et] = *(const short8*)(hid + (size_t)(eloc0 + et * 16 + l16) * HSTRIDE + k0);
#pragma unroll
        for (int ft = 0; ft < 4; ++ft)
            aw[ft] = *(const short8*)(wbuf + ((wf * 4 + ft) * 4 + ks) * 512
                                      + ((lane ^ (ks << 1)) * 8));
#pragma unroll
        for (int ft = 0; ft < 4; ++ft)
#pragma unroll
            for (int et = 0; et < 2; ++et)
                acc[ft][et] = __builtin_amdgcn_mfma_f32_16x16x32_bf16(
                    aw[ft], bh[et], acc[ft][et], 0, 0, 0);
    }
#pragma unroll
    for (int ft = 0; ft < 4; ++ft) {
        const int feat = fbase + ft * 16 + quad * 4;
        floatx4 bv = (floatx4){0.f, 0.f, 0.f, 0.f};
        if (b2a) bv = *(const floatx4*)(b2a + feat);
#pragma unroll
        for (int et = 0; et < 2; ++et) {
            const int e = e0 + et * 16 + l16;
            __align__(8) __hip_bfloat16 tmp[4];
#pragma unroll
            for (int r = 0; r < 4; ++r)
                tmp[r] = __float2bfloat16(acc[ft][et][r] + bv[r]);
            *(short4v*)((nn ? Q1n : Q1e) + (size_t)e * F + feat) = *(const short4v*)tmp;
        }
    }
    __syncthreads();
    stage_write_frag(wbuf, t, wreg);    // W1b
    __syncthreads();

    // ===== layer B1 =====
    stage_issue(W2b, t, wreg);
    __builtin_amdgcn_sched_barrier(0);
#pragma unroll
    for (int ft = 0; ft < 4; ++ft)
#pragma unroll
        for (int et = 0; et < 2; ++et)
            acc[ft][et] = (floatx4){0.f, 0.f, 0.f, 0.f};
#pragma unroll
    for (int ks = 0; ks < 4; ++ks) {
        short8 aw[4];
#pragma unroll
        for (int ft = 0; ft < 4; ++ft)
            aw[ft] = *(const short8*)(wbuf + ((wf * 4 + ft) * 4 + ks) * 512
                                      + ((lane ^ (ks << 1)) * 8));
#pragma unroll
        for (int ft = 0; ft < 4; ++ft)
#pragma unroll
            for (int et = 0; et < 2; ++et)
                acc[ft][et] = __builtin_amdgcn_mfma_f32_16x16x32_bf16(
                    aw[ft], bxk[ks][et], acc[ft][et], 0, 0, 0);
    }
#pragma unroll
    for (int ft = 0; ft < 4; ++ft) {
        const int feat = fbase + ft * 16 + quad * 4;
        floatx4 bv = (floatx4){0.f, 0.f, 0.f, 0.f};
        if (b1b) bv = *(const floatx4*)(b1b + feat);
#pragma unroll
        for (int et = 0; et < 2; ++et) {
            const int el = eloc0 + et * 16 + l16;
            __align__(8) __hip_bfloat16 tmp[4];
#pragma unroll
            for (int r = 0; r < 4; ++r)
                tmp[r] = __float2bfloat16(silu_f(acc[ft][et][r] + bv[r]));
            *(short4v*)(hid + (size_t)el * HSTRIDE + feat) = *(const short4v*)tmp;
        }
    }
    __syncthreads();
    stage_write_frag(wbuf, t, wreg);    // W2b
    __syncthreads();

    // ===== layer B2 =====
#pragma unroll
    for (int ft = 0; ft < 4; ++ft)
#pragma unroll
        for (int et = 0; et < 2; ++et)
            acc[ft][et] = (floatx4){0.f, 0.f, 0.f, 0.f};
#pragma unroll
    for (int ks = 0; ks < 4; ++ks) {
        const int k0 = ks * 32 + quad * 8;
        short8 bh[2], aw[4];
#pragma unroll
        for (int et = 0; et < 2; ++et)
            bh[et] = *(const short8*)(hid + (size_t)(eloc0 + et * 16 + l16) * HSTRIDE + k0);
#pragma unroll
        for (int ft = 0; ft < 4; ++ft)
            aw[ft] = *(const short8*)(wbuf + ((wf * 4 + ft) * 4 + ks) * 512
                                      + ((lane ^ (ks << 1)) * 8));
#pragma unroll
        for (int ft = 0; ft < 4; ++ft)
#pragma unroll
            for (int et = 0; et < 2; ++et)
                acc[ft][et] = __builtin_amdgcn_mfma_f32_16x16x32_bf16(
                    aw[ft], bh[et], acc[ft][et], 0, 0, 0);
    }
#pragma unroll
    for (int ft = 0; ft < 4; ++ft) {
        const int feat = fbase + ft * 16 + quad * 4;
        floatx4 bv = (floatx4){0.f, 0.f, 0.f, 0.f};
        if (b2b) bv = *(const floatx4*)(b2b + feat);
#pragma unroll
        for (int et = 0; et < 2; ++et) {
            const int e = e0 + et * 16 + l16;
            if (!nn) {
                __align__(8) __hip_bfloat16 tmp[4];
#pragma unroll
                for (int r = 0; r < 4; ++r)
                    tmp[r] = __float2bfloat16(acc[ft][et][r] + bv[r]);
                *(short4v*)(Q2e + (size_t)e * F + feat) = *(const short4v*)tmp;
            } else {
                floatx4 v;
#pragma unroll
                for (int r = 0; r < 4; ++r) v[r] = acc[ft][et][r] + bv[r];
                *(floatx4*)(Q2n + (size_t)e * F + feat) = v;
            }
        }
    }
}

// ---------------- edge invariant message: LDS-staged h rows -----------------
__global__ __launch_bounds__(256) void edge_inv_mfma_kernel(
    const __hip_bfloat16* __restrict__ dist_p,
    const __hip_bfloat16* __restrict__ empWt,   // [128 feat][32 k]
    const float* __restrict__ emp_b, const __hip_bfloat16* __restrict__ h,
    const int* __restrict__ src_p, const int* __restrict__ dst_p,
    __hip_bfloat16* __restrict__ Xbf, int E)
{
    __shared__ __hip_bfloat16 hrows[256 * HROWS_STRIDE];
    __shared__ int ridx[256];
    const int t = threadIdx.x;
    const int wave = t >> 6;
    const int lane = t & 63;
    const int quad = lane >> 4;
    const int l16  = lane & 15;
    const int e0b = blockIdx.x * 128;
    const int e0 = e0b + wave * 32;

    {
        const int le = (t < 128) ? t : (t - 128);
        const int e = e0b + le;
        const int idx = (e < E) ? ((t < 128) ? src_p[e] : dst_p[e]) : 0;
        ridx[t] = idx;
    }
    __syncthreads();

#pragma unroll
    for (int i = 0; i < 16; ++i) {
        const int idx = i * 256 + t;
        const int r = idx >> 4, part = idx & 15;
        const short8 v = *(const short8*)(h + (size_t)ridx[r] * F + part * 8);
        const short4v lo = __builtin_shufflevector(v, v, 0, 1, 2, 3);
        const short4v hi = __builtin_shufflevector(v, v, 4, 5, 6, 7);
        *(short4v*)(hrows + (size_t)r * HROWS_STRIDE + part * 8)     = lo;
        *(short4v*)(hrows + (size_t)r * HROWS_STRIDE + part * 8 + 4) = hi;
    }

    short8 bx[2], aw[8];
#pragma unroll
    for (int et = 0; et < 2; ++et)
        bx[et] = *(const short8*)(dist_p + (size_t)(e0 + et * 16 + l16) * KP + quad * 8);
#pragma unroll
    for (int ft = 0; ft < 8; ++ft)
        aw[ft] = *(const short8*)(empWt + (size_t)(ft * 16 + l16) * KP + quad * 8);

    floatx4 acc[8][2];
#pragma unroll
    for (int ft = 0; ft < 8; ++ft)
#pragma unroll
        for (int et = 0; et < 2; ++et)
            acc[ft][et] = __builtin_amdgcn_mfma_f32_16x16x32_bf16(
                aw[ft], bx[et], (floatx4){0.f, 0.f, 0.f, 0.f}, 0, 0, 0);

    __syncthreads();   // hrows complete

    int eidx[2];
#pragma unroll
    for (int et = 0; et < 2; ++et) eidx[et] = e0 + et * 16 + l16;

#pragma unroll
    for (int ft = 0; ft < 8; ++ft) {
        const int feat = ft * 16 + quad * 4;
        const floatx4 bv = *(const floatx4*)(emp_b + feat);
#pragma unroll
        for (int et = 0; et < 2; ++et) {
            const int le = wave * 32 + et * 16 + l16;      // local edge 0..127
            const short4v hs = *(const short4v*)(hrows + (size_t)le * HROWS_STRIDE + feat);
            const short4v hd = *(const short4v*)(hrows + (size_t)(128 + le) * HROWS_STRIDE + feat);
            const bool v = eidx[et] < E;
            __align__(8) __hip_bfloat16 tmp[4];
#pragma unroll
            for (int r = 0; r < 4; ++r) {
                const float m = v ? (acc[ft][et][r] + bv[r]) * bfs2f(hs[r]) * bfs2f(hd[r])
                                  : 0.0f;
                tmp[r] = __float2bfloat16(m);
            }
            *(short4v*)(Xbf + (size_t)eidx[et] * F + feat) = *(const short4v*)tmp;
        }
    }
}

// ---------------- merged prep: weights + empW + atom cast/pad + zero -------
__global__ void prep_all_kernel(
    const float* __restrict__ W0, const float* __restrict__ W1,
    const float* __restrict__ W2, const float* __restrict__ W3,
    const float* __restrict__ W4, const float* __restrict__ W5,
    const float* __restrict__ W6, const float* __restrict__ W7,
    const float* __restrict__ W8, const float* __restrict__ W9,
    const float* __restrict__ emp_W, const float* __restrict__ atom_node,
    __hip_bfloat16* __restrict__ Wt, __hip_bfloat16* __restrict__ empWt,
    __hip_bfloat16* __restrict__ atom_bf, __hip_bfloat16* __restrict__ atom_new_bf,
    int* __restrict__ counts, int nF, int nPadTot, int N)
{
    const int WTOT = 10 * F * F;      // 163840
    const int ETOT = F * KP;          // 4096
    const int S2 = WTOT + ETOT;
    const int S3 = S2 + nPadTot;
    const int S4 = S3 + (nPadTot - nF);
    const int total = S4 + N;
    const int stride = gridDim.x * blockDim.x;
    for (int i = blockIdx.x * blockDim.x + threadIdx.x; i < total; i += stride) {
        if (i < WTOT) {
            const int w = i >> 14;
            const int idx = i & (F * F - 1);
            const int n = idx >> 7, k = idx & 127;
            const float* W = (w == 0) ? W0 : (w == 1) ? W1 : (w == 2) ? W2
                           : (w == 3) ? W3 : (w == 4) ? W4 : (w == 5) ? W5
                           : (w == 6) ? W6 : (w == 7) ? W7 : (w == 8) ? W8 : W9;
            Wt[i] = __float2bfloat16(W[k * F + n]);
        } else if (i < S2) {
            const int j = i - WTOT;
            const int n = j >> 5, k = j & (KP - 1);
            empWt[j] = __float2bfloat16(k < NB ? emp_W[k * F + n] : 0.0f);
        } else if (i < S3) {
            const int j = i - S2;
            atom_bf[j] = __float2bfloat16(j < nF ? atom_node[j] : 0.0f);
        } else if (i < S4) {
            atom_new_bf[(i - S3) + nF] = __float2bfloat16(0.0f);
        } else {
            counts[i - S4] = 0;
        }
    }
}

// ---------------- CSR build (edges grouped by src) ----------------

__global__ void csr_count_kernel(const int* __restrict__ src,
                                 int* __restrict__ counts, int E) {
    const int stride = gridDim.x * blockDim.x;
    for (int e = blockIdx.x * blockDim.x + threadIdx.x; e < E; e += stride)
        atomicAdd(&counts[src[e]], 1);
}

__global__ __launch_bounds__(1024) void csr_scan_kernel(
    const int* __restrict__ counts, int* __restrict__ offsets,
    int* __restrict__ cursor, int N)
{
    constexpr int T = 1024;
    const int t = threadIdx.x;
    const int per = (N + T - 1) / T;
    const int base = t * per;
    int lsum = 0;
    for (int i = 0; i < per; ++i) {
        int idx = base + i;
        if (idx < N) lsum += counts[idx];
    }
    __shared__ int s[T];
    s[t] = lsum;
    __syncthreads();
    for (int off = 1; off < T; off <<= 1) {
        int v = (t >= off) ? s[t - off] : 0;
        __syncthreads();
        s[t] += v;
        __syncthreads();
    }
    int run = s[t] - lsum;
    for (int i = 0; i < per; ++i) {
        int idx = base + i;
        if (idx < N) {
            offsets[idx] = run;
            cursor[idx] = run;
            run += counts[idx];
        }
    }
    if (t == T - 1) offsets[N] = run;
}

__global__ void csr_perm_kernel(const int* __restrict__ src,
                                const int* __restrict__ dst,
                                const float* __restrict__ disp_edge,
                                const float* __restrict__ dist_edge,
                                int* __restrict__ cursor,
                                int* __restrict__ src_p,
                                int* __restrict__ dst_p,
                                float* __restrict__ de_p,
                                __hip_bfloat16* __restrict__ dist_p, int E) {
    const int stride = gridDim.x * blockDim.x;
    for (int e = blockIdx.x * blockDim.x + threadIdx.x; e < E; e += stride) {
        const int s = src[e];
        const int pos = atomicAdd(&cursor[s], 1);
        src_p[pos] = s;
        dst_p[pos] = dst[e];
        de_p[3 * pos + 0] = disp_edge[3 * e + 0];
        de_p[3 * pos + 1] = disp_edge[3 * e + 1];
        de_p[3 * pos + 2] = disp_edge[3 * e + 2];
        __align__(16) __hip_bfloat16 tmp[KP];
#pragma unroll
        for (int k = 0; k < KP; ++k)
            tmp[k] = __float2bfloat16(k < NB ? dist_edge[(size_t)e * NB + k] : 0.0f);
#pragma unroll
        for (int q = 0; q < 4; ++q)
            *(short8*)(dist_p + (size_t)pos * KP + q * 8) = ((const short8*)tmp)[q];
    }
}

// ---------- per-node gathers: wave-per-node, 2 features/lane (4B+ loads) ----

__global__ __launch_bounds__(256) void gather_inv_kernel(
    const __hip_bfloat16* __restrict__ inv_msg, const int* __restrict__ offsets,
    const float* __restrict__ atom,
    float* __restrict__ atom_new, __hip_bfloat16* __restrict__ atom_new_bf, int N)
{
    const int n = blockIdx.x * 4 + (threadIdx.x >> 6);
    if (n >= N) return;
    const int f0 = (threadIdx.x & 63) * 2;
    const int p0 = offsets[n], p1 = offsets[n + 1];
    float a0 = 0.0f, a1 = 0.0f;
    for (int p = p0; p < p1; ++p) {
        const unsigned int u = *(const unsigned int*)(inv_msg + (size_t)p * F + f0);
        a0 += lo_bf(u);
        a1 += hi_bf(u);
    }
    const float2 av = *(const float2*)(atom + (size_t)n * F + f0);
    const float v0 = av.x + a0, v1 = av.y + a1;
    *(float2*)(atom_new + (size_t)n * F + f0) = make_float2(v0, v1);
    __hip_bfloat16 b0 = __float2bfloat16(v0), b1 = __float2bfloat16(v1);
    *(ushort2*)(atom_new_bf + (size_t)n * F + f0) =
        make_ushort2(*(unsigned short*)&b0, *(unsigned short*)&b1);
}

// eq1 gather + out_force + packed {bf16(disp_node), bf16(eq3i*agg1)} table
__global__ __launch_bounds__(256) void gather_eq1_kernel(
    const __hip_bfloat16* __restrict__ eqm, const float* __restrict__ de_p,
    const int* __restrict__ offsets,
    const float* __restrict__ force, const float* __restrict__ disp_node,
    const __hip_bfloat16* __restrict__ eq3i_bf,
    float* __restrict__ out_force, ushort2* __restrict__ pk, int N)
{
    const int n = blockIdx.x * 4 + (threadIdx.x >> 6);
    if (n >= N) return;
    const int f0 = (threadIdx.x & 63) * 2;
    const int p0 = offsets[n], p1 = offsets[n + 1];
    float a00 = 0.f, a01 = 0.f, a10 = 0.f, a11 = 0.f, a20 = 0.f, a21 = 0.f;
    for (int p = p0; p < p1; ++p) {
        const unsigned int u = *(const unsigned int*)(eqm + (size_t)p * F + f0);
        const float m0 = lo_bf(u), m1 = hi_bf(u);
        const float d0 = de_p[(size_t)p * 3 + 0];
        const float d1 = de_p[(size_t)p * 3 + 1];
        const float d2 = de_p[(size_t)p * 3 + 2];
        a00 = fmaf(m0, d0, a00); a01 = fmaf(m1, d0, a01);
        a10 = fmaf(m0, d1, a10); a11 = fmaf(m1, d1, a11);
        a20 = fmaf(m0, d2, a20); a21 = fmaf(m1, d2, a21);
    }
    const unsigned int ug = *(const unsigned int*)(eq3i_bf + (size_t)n * F + f0);
    const float g0 = lo_bf(ug), g1 = hi_bf(ug);
    const size_t b = (size_t)n * 3 * F + f0;

    float2 f;
    f = *(const float2*)(force + b);
    *(float2*)(out_force + b) = make_float2(f.x + a00, f.y + a01);
    f = *(const float2*)(force + b + F);
    *(float2*)(out_force + b + F) = make_float2(f.x + a10, f.y + a11);
    f = *(const float2*)(force + b + 2 * F);
    *(float2*)(out_force + b + 2 * F) = make_float2(f.x + a20, f.y + a21);

    float2 dn;
    dn = *(const float2*)(disp_node + b);
    *(uint2*)(pk + b) = make_uint2(pack_bf2(dn.x, g0 * a00), pack_bf2(dn.y, g1 * a01));
    dn = *(const float2*)(disp_node + b + F);
    *(uint2*)(pk + b + F) = make_uint2(pack_bf2(dn.x, g0 * a10), pack_bf2(dn.y, g1 * a11));
    dn = *(const float2*)(disp_node + b + 2 * F);
    *(uint2*)(pk + b + 2 * F) = make_uint2(pack_bf2(dn.x, g0 * a20), pack_bf2(dn.y, g1 * a21));
}

// merged eq2+eq3 gather + final update + LayerNorm
__global__ __launch_bounds__(256) void gather_eq23_ln_kernel(
    const __hip_bfloat16* __restrict__ eqm2, const ushort2* __restrict__ pk,
    const float* __restrict__ disp_node,
    const int* __restrict__ dst_p, const int* __restrict__ offsets,
    const float* __restrict__ atom_new, const float* __restrict__ upd,
    const float* __restrict__ out_force,
    const float* __restrict__ ln_g, const float* __restrict__ ln_b,
    float* __restrict__ out_disp, float* __restrict__ out_atom, int N)
{
    const int n = blockIdx.x * 4 + (threadIdx.x >> 6);
    if (n >= N) return;
    const int f0 = (threadIdx.x & 63) * 2;
    const int p0 = offsets[n], p1 = offsets[n + 1];
    float a00 = 0.f, a01 = 0.f, a10 = 0.f, a11 = 0.f, a20 = 0.f, a21 = 0.f;
    int d = (p0 < p1) ? dst_p[p0] : 0;
    for (int p = p0; p < p1; ++p) {
        const int dn = (p + 1 < p1) ? dst_p[p + 1] : 0;
        const unsigned int u = *(const unsigned int*)(eqm2 + (size_t)p * F + f0);
        const float m0 = lo_bf(u), m1 = hi_bf(u);
        const size_t pb = (size_t)d * 3 * F + f0;
        const uint2 c0 = *(const uint2*)(pk + pb);
        const uint2 c1 = *(const uint2*)(pk + pb + F);
        const uint2 c2 = *(const uint2*)(pk + pb + 2 * F);
        a00 += m0 * lo_bf(c0.x) + hi_bf(c0.x);
        a01 += m1 * lo_bf(c0.y) + hi_bf(c0.y);
        a10 += m0 * lo_bf(c1.x) + hi_bf(c1.x);
        a11 += m1 * lo_bf(c1.y) + hi_bf(c1.y);
        a20 += m0 * lo_bf(c2.x) + hi_bf(c2.x);
        a21 += m1 * lo_bf(c2.y) + hi_bf(c2.y);
        d = dn;
    }
    const size_t b = (size_t)n * 3 * F + f0;
    float2 dn2;
    dn2 = *(const float2*)(disp_node + b);
    const float2 od0 = make_float2(dn2.x + a00, dn2.y + a01);
    dn2 = *(const float2*)(disp_node + b + F);
    const float2 od1 = make_float2(dn2.x + a10, dn2.y + a11);
    dn2 = *(const float2*)(disp_node + b + 2 * F);
    const float2 od2 = make_float2(dn2.x + a20, dn2.y + a21);
    *(float2*)(out_disp + b)         = od0;
    *(float2*)(out_disp + b + F)     = od1;
    *(float2*)(out_disp + b + 2 * F) = od2;

    const float2 fo0 = *(const float2*)(out_force + b);
    const float2 fo1 = *(const float2*)(out_force + b + F);
    const float2 fo2 = *(const float2*)(out_force + b + 2 * F);
    const float s0 = -(fo0.x * od0.x + fo1.x * od1.x + fo2.x * od2.x);
    const float s1 = -(fo0.y * od0.y + fo1.y * od1.y + fo2.y * od2.y);

    const float2 an = *(const float2*)(atom_new + (size_t)n * F + f0);
    const float2 up = *(const float2*)(upd + (size_t)n * F + f0);
    const float y0 = an.x + up.x * s0;
    const float y1 = an.y + up.y * s1;

    float sy = y0 + y1, syy = y0 * y0 + y1 * y1;
#pragma unroll
    for (int m = 1; m < 64; m <<= 1) {
        sy  += __shfl_xor(sy, m);
        syy += __shfl_xor(syy, m);
    }
    const float mu = sy * (1.0f / F);
    float var = syy * (1.0f / F) - mu * mu;
    if (var < 0.0f) var = 0.0f;
    const float rstd = rsqrtf(var + 1e-5f);

    const float2 gg = *(const float2*)(ln_g + f0);
    const float2 bb = *(const float2*)(ln_b + f0);
    *(float2*)(out_atom + (size_t)n * F + f0) =
        make_float2((y0 - mu) * rstd * gg.x + bb.x,
                    (y1 - mu) * rstd * gg.y + bb.y);
}

extern "C" void kernel_launch(void* const* d_in, const int* in_sizes, int n_in,
                              void* d_out, int out_size, void* d_ws, size_t ws_size,
                              hipStream_t stream)
{
    const float* atom_node  = (const float*)d_in[0];
    const float* force_node = (const float*)d_in[1];
    const float* disp_node  = (const float*)d_in[2];
    const float* disp_edge  = (const float*)d_in[3];
    const float* dist_edge  = (const float*)d_in[4];
    const int*   edge_index = (const int*)d_in[5];
    const float* nmp_W1 = (const float*)d_in[6];
    const float* nmp_b1 = (const float*)d_in[7];
    const float* nmp_W2 = (const float*)d_in[8];
    const float* nmp_b2 = (const float*)d_in[9];
    const float* emp_W  = (const float*)d_in[10];
    const float* emp_b  = (const float*)d_in[11];
    const float* eq1_W1 = (const float*)d_in[12];
    const float* eq1_b1 = (const float*)d_in[13];
    const float* eq1_W2 = (const float*)d_in[14];
    const float* eq1_b2 = (const float*)d_in[15];
    const float* eq2_W1 = (const float*)d_in[16];
    const float* eq2_b1 = (const float*)d_in[17];
    const float* eq2_W2 = (const float*)d_in[18];
    const float* eq2_b2 = (const float*)d_in[19];
    const float* eq3_W1 = (const float*)d_in[20];
    const float* eq3_W2 = (const float*)d_in[21];
    const float* upd_W1 = (const float*)d_in[22];
    const float* upd_b1 = (const float*)d_in[23];
    const float* upd_W2 = (const float*)d_in[24];
    const float* upd_b2 = (const float*)d_in[25];
    const float* ln_g   = (const float*)d_in[26];
    const float* ln_b   = (const float*)d_in[27];

    const int N = in_sizes[0] / F;            // 10000
    const int E = in_sizes[4] / NB;           // 200000
    const int Mp  = ((E + 127) / 128) * 128;  // 200064
    const int Mp2 = ((N + 127) / 128) * 128;  // 10112
    const int* src = edge_index;
    const int* dst = edge_index + E;
    const int nF = N * F, n3F = N * 3 * F;

    float* out_atom  = (float*)d_out;
    float* out_force = out_atom + (size_t)nF;
    float* out_disp  = out_force + (size_t)n3F;

    // ---- workspace layout ----
    char* p = (char*)d_ws;
    int* counts  = (int*)p;
    int* offsets = counts + N;
    int* cursor  = offsets + (N + 1);
    int* src_p   = cursor + N;
    int* dst_p   = src_p + E;
    size_t off = (size_t)(3 * N + 1 + 2 * E) * sizeof(int);
    off = (off + 63) & ~(size_t)63;
    float* de_p = (float*)(p + off); off += (size_t)3 * E * sizeof(float);
    off = (off + 63) & ~(size_t)63;
    __hip_bfloat16* dist_p = (__hip_bfloat16*)(p + off); off += (size_t)Mp * KP * 2;
    __hip_bfloat16* empWt  = (__hip_bfloat16*)(p + off); off += (size_t)F * KP * 2;

    __hip_bfloat16* h_bf        = (__hip_bfloat16*)(p + off); off += (size_t)Mp2 * F * 2;
    __hip_bfloat16* atom_bf     = (__hip_bfloat16*)(p + off); off += (size_t)Mp2 * F * 2;
    __hip_bfloat16* atom_new_bf = (__hip_bfloat16*)(p + off); off += (size_t)Mp2 * F * 2;
    __hip_bfloat16* eq3i_bf     = (__hip_bfloat16*)(p + off); off += (size_t)Mp2 * F * 2;
    off = (off + 63) & ~(size_t)63;
    float* atom_new = (float*)(p + off); off += (size_t)nF * 4;
    float* upd_f    = (float*)(p + off); off += (size_t)Mp2 * F * 4;
    ushort2* pk     = (ushort2*)(p + off); off += (size_t)n3F * sizeof(ushort2);
    off = (off + 63) & ~(size_t)63;
    __hip_bfloat16* Xbf = (__hip_bfloat16*)(p + off); off += (size_t)Mp * F * 2;
    __hip_bfloat16* Q1  = (__hip_bfloat16*)(p + off); off += (size_t)Mp * F * 2;
    __hip_bfloat16* Q2  = Xbf;   // alias: edge blocks read their X rows before writing Q2 rows
    __hip_bfloat16* Wt  = (__hip_bfloat16*)(p + off); // 10*F*F bf16
    __hip_bfloat16* Wt_eq1a = Wt + 0 * F * F;
    __hip_bfloat16* Wt_eq1b = Wt + 1 * F * F;
    __hip_bfloat16* Wt_eq2a = Wt + 2 * F * F;
    __hip_bfloat16* Wt_eq2b = Wt + 3 * F * F;
    __hip_bfloat16* Wt_nmpa = Wt + 4 * F * F;
    __hip_bfloat16* Wt_nmpb = Wt + 5 * F * F;
    __hip_bfloat16* Wt_eq3a = Wt + 6 * F * F;
    __hip_bfloat16* Wt_eq3b = Wt + 7 * F * F;
    __hip_bfloat16* Wt_upda = Wt + 8 * F * F;
    __hip_bfloat16* Wt_updb = Wt + 9 * F * F;

    // ---- merged prep (weights + empW + atom cast/pad + atom_new pad + zero counts)
    prep_all_kernel<<<1024, 256, 0, stream>>>(
        eq1_W1, eq1_W2, eq2_W1, eq2_W2, nmp_W1, nmp_W2, eq3_W1, eq3_W2,
        upd_W1, upd_W2, emp_W, atom_node,
        Wt, empWt, atom_bf, atom_new_bf, counts, nF, Mp2 * F, N);

    // ---- CSR build ----
    csr_count_kernel<<<256, 256, 0, stream>>>(src, counts, E);
    csr_scan_kernel<<<1, 1024, 0, stream>>>(counts, offsets, cursor, N);
    csr_perm_kernel<<<256, 256, 0, stream>>>(src, dst, disp_edge, dist_edge,
                                             cursor, src_p, dst_p, de_p, dist_p, E);

    // ---- h = mlp2(atom_node, nmp), LDS-staged weights ----
    mlp_staged_kernel<<<Mp2 / 128, 512, 0, stream>>>(
        atom_bf, Wt_nmpa, nmp_b1, Wt_nmpb, nmp_b2, h_bf);

    // ---- invariant message (MFMA + LDS-staged h products) + node aggregation
    edge_inv_mfma_kernel<<<Mp / 128, 256, 0, stream>>>(
        dist_p, empWt, emp_b, h_bf, src_p, dst_p, Xbf, E);
    gather_inv_kernel<<<(N + 3) / 4, 256, 0, stream>>>(Xbf, offsets, atom_node,
                                                       atom_new, atom_new_bf, N);

    // ---- merged dual MLPs: edge eq1+eq2 (1563 tiles) + node eq3+upd (79) ----
    {
        const int ntileE = Mp / 128;
        const int ntileN = Mp2 / 128;
        dual_mlp2_kernel<<<ntileE + ntileN, 512, 0, stream>>>(
            Xbf, Wt_eq1a, eq1_b1, Wt_eq1b, eq1_b2,
            Wt_eq2a, eq2_b1, Wt_eq2b, eq2_b2, Q1, Q2, ntileE,
            atom_new_bf, Wt_eq3a, Wt_eq3b,
            Wt_upda, upd_b1, Wt_updb, upd_b2, eq3i_bf, upd_f);
    }

    // ---- gathers (+ fused LN in eq23) ----
    gather_eq1_kernel<<<(N + 3) / 4, 256, 0, stream>>>(
        Q1, de_p, offsets, force_node, disp_node, eq3i_bf, out_force, pk, N);
    gather_eq23_ln_kernel<<<(N + 3) / 4, 256, 0, stream>>>(
        Q2, pk, disp_node, dst_p, offsets, atom_new, upd_f, out_force,
        ln_g, ln_b, out_disp, out_atom, N);
}

// Round 12
// 411.675 us; speedup vs baseline: 1.0576x; 1.0025x over previous
//
#include <hip/hip_runtime.h>
#include <hip/hip_bf16.h>

#define F 128
#define NB 20
#define KP 32          // padded K for the edge-embedding MFMA
#define HSTRIDE 136
#define HROWS_STRIDE 140   // h-row LDS stride (280B): 4-way-max bank aliasing for b64

typedef __attribute__((ext_vector_type(8))) short short8;
typedef __attribute__((ext_vector_type(4))) short short4v;
typedef __attribute__((ext_vector_type(4))) float floatx4;

__device__ __forceinline__ float silu_f(float x) {
    return x * __builtin_amdgcn_rcpf(1.0f + __expf(-x));
}
__device__ __forceinline__ float bfs2f(short s) {
    unsigned int u = ((unsigned int)(unsigned short)s) << 16;
    float f; __builtin_memcpy(&f, &u, 4); return f;
}
__device__ __forceinline__ float lo_bf(unsigned int u) { return bfs2f((short)(u & 0xFFFF)); }
__device__ __forceinline__ float hi_bf(unsigned int u) { return bfs2f((short)(u >> 16)); }
__device__ __forceinline__ unsigned int pack_bf2(float d, float v) {
    __hip_bfloat16 db = __float2bfloat16(d), vb = __float2bfloat16(v);
    return (unsigned int)*(unsigned short*)&db
         | ((unsigned int)*(unsigned short*)&vb << 16);
}

// Cooperative weight staging (512 threads): 128x128 bf16 matrix global->reg.
__device__ __forceinline__ void stage_issue(const __hip_bfloat16* W, int t,
                                            short8 wreg[4]) {
#pragma unroll
    for (int r = 0; r < 4; ++r)
        wreg[r] = *(const short8*)(W + (size_t)(r * 512 + t) * 8);
}
// Fragment-major LDS layout: frag (ft*4+ks) holds 64 lanes x 16B contiguous,
// so the MFMA aw ds_read_b128 is lane-contiguous.
__device__ __forceinline__ void stage_write_frag(__hip_bfloat16* wbuf, int t,
                                                 const short8 wreg[4]) {
#pragma unroll
    for (int r = 0; r < 4; ++r) {
        const int c0 = r * 512 + t;           // 16B chunk id in row-major W
        const int n = c0 >> 4, p = c0 & 15;   // row, 16B part (k = p*8..)
        const int ks = p >> 2;
        const int frag = (n >> 4) * 4 + ks;   // ft_global*4 + ks
        const int lam = (((p & 3) * 16) + (n & 15)) ^ (ks << 1);
        *(short8*)(wbuf + (size_t)frag * 512 + lam * 8) = wreg[r];
    }
}

// Intra-wave hidden exchange: lane (quad,l16) holds features {ft*16+quad*4+r}
// of row l16 as bf16 pairs hpk[ft]. The layer-2 B fragment for k-slice ks
// needs features ks*32+quad*8..+8 of row l16: chunk hpk[2ks+(quad>>1)] from
// lanes 2(quad&1)*16+l16 and +16. All compile-time hpk indices + cndmask.
__device__ __forceinline__ short8 hshuffle(const uint2 h0, const uint2 h1,
                                           int quad, int l16) {
    const int srcA = (2 * (quad & 1)) * 16 + l16;
    const int srcB = srcA + 16;
    const bool hi = (quad >> 1) & 1;
    const unsigned a0x = (unsigned)__shfl((int)h0.x, srcA);
    const unsigned a0y = (unsigned)__shfl((int)h0.y, srcA);
    const unsigned a1x = (unsigned)__shfl((int)h1.x, srcA);
    const unsigned a1y = (unsigned)__shfl((int)h1.y, srcA);
    const unsigned b0x = (unsigned)__shfl((int)h0.x, srcB);
    const unsigned b0y = (unsigned)__shfl((int)h0.y, srcB);
    const unsigned b1x = (unsigned)__shfl((int)h1.x, srcB);
    const unsigned b1y = (unsigned)__shfl((int)h1.y, srcB);
    uint4 u;
    u.x = hi ? a1x : a0x;
    u.y = hi ? a1y : a0y;
    u.z = hi ? b1x : b0x;
    u.w = hi ? b1y : b0y;
    short8 out;
    __builtin_memcpy(&out, &u, 16);
    return out;
}

// ---------------- single 2-layer MLP, LDS-staged weights (nmp) -------------
// (old hid-based structure; only ~8us, left untouched)
__global__ __launch_bounds__(512, 4) void mlp_staged_kernel(
    const __hip_bfloat16* __restrict__ X,
    const __hip_bfloat16* __restrict__ W1, const float* __restrict__ b1,
    const __hip_bfloat16* __restrict__ W2, const float* __restrict__ b2,
    __hip_bfloat16* __restrict__ Y)
{
    __shared__ __hip_bfloat16 hid[128 * HSTRIDE];
    __shared__ __hip_bfloat16 wbuf[32 * 512];
    const int t = threadIdx.x;
    const int wave = t >> 6;
    const int rg   = wave >> 1;
    const int wf   = wave & 1;
    const int lane = t & 63;
    const int quad = lane >> 4;
    const int l16  = lane & 15;
    const int eloc0 = rg * 32;
    const int e0 = blockIdx.x * 128 + eloc0;
    const int fbase = wf * 64;

    short8 bxk[4][2];
#pragma unroll
    for (int ks = 0; ks < 4; ++ks)
#pragma unroll
        for (int et = 0; et < 2; ++et)
            bxk[ks][et] = *(const short8*)(X + (size_t)(e0 + et * 16 + l16) * F
                                           + ks * 32 + quad * 8);

    short8 wreg[4];
    floatx4 acc[4][2];

    stage_issue(W1, t, wreg);
    stage_write_frag(wbuf, t, wreg);
    __syncthreads();

    // ===== layer 1 =====
    stage_issue(W2, t, wreg);     // prefetch under layer-1 compute
    __builtin_amdgcn_sched_barrier(0);
#pragma unroll
    for (int ft = 0; ft < 4; ++ft)
#pragma unroll
        for (int et = 0; et < 2; ++et)
            acc[ft][et] = (floatx4){0.f, 0.f, 0.f, 0.f};
#pragma unroll
    for (int ks = 0; ks < 4; ++ks) {
        short8 aw[4];
#pragma unroll
        for (int ft = 0; ft < 4; ++ft)
            aw[ft] = *(const short8*)(wbuf + (((wf * 4 + ft) * 4) + ks) * 512
                                      + ((lane ^ (ks << 1)) * 8));
#pragma unroll
        for (int ft = 0; ft < 4; ++ft)
#pragma unroll
            for (int et = 0; et < 2; ++et)
                acc[ft][et] = __builtin_amdgcn_mfma_f32_16x16x32_bf16(
                    aw[ft], bxk[ks][et], acc[ft][et], 0, 0, 0);
    }
#pragma unroll
    for (int ft = 0; ft < 4; ++ft) {
        const int feat = fbase + ft * 16 + quad * 4;
        const floatx4 bv = *(const floatx4*)(b1 + feat);
#pragma unroll
        for (int et = 0; et < 2; ++et) {
            const int el = eloc0 + et * 16 + l16;
            __align__(8) __hip_bfloat16 tmp[4];
#pragma unroll
            for (int r = 0; r < 4; ++r)
                tmp[r] = __float2bfloat16(silu_f(acc[ft][et][r] + bv[r]));
            *(short4v*)(hid + (size_t)el * HSTRIDE + feat) = *(const short4v*)tmp;
        }
    }
    __syncthreads();
    stage_write_frag(wbuf, t, wreg);    // W2 -> wbuf
    __syncthreads();

    // ===== layer 2 =====
#pragma unroll
    for (int ft = 0; ft < 4; ++ft)
#pragma unroll
        for (int et = 0; et < 2; ++et)
            acc[ft][et] = (floatx4){0.f, 0.f, 0.f, 0.f};
#pragma unroll
    for (int ks = 0; ks < 4; ++ks) {
        const int k0 = ks * 32 + quad * 8;
        short8 bh[2], aw[4];
#pragma unroll
        for (int et = 0; et < 2; ++et)
            bh[et] = *(const short8*)(hid + (size_t)(eloc0 + et * 16 + l16) * HSTRIDE + k0);
#pragma unroll
        for (int ft = 0; ft < 4; ++ft)
            aw[ft] = *(const short8*)(wbuf + (((wf * 4 + ft) * 4) + ks) * 512
                                      + ((lane ^ (ks << 1)) * 8));
#pragma unroll
        for (int ft = 0; ft < 4; ++ft)
#pragma unroll
            for (int et = 0; et < 2; ++et)
                acc[ft][et] = __builtin_amdgcn_mfma_f32_16x16x32_bf16(
                    aw[ft], bh[et], acc[ft][et], 0, 0, 0);
    }
#pragma unroll
    for (int ft = 0; ft < 4; ++ft) {
        const int feat = fbase + ft * 16 + quad * 4;
        const floatx4 bv = *(const floatx4*)(b2 + feat);
#pragma unroll
        for (int et = 0; et < 2; ++et) {
            const int e = e0 + et * 16 + l16;
            __align__(8) __hip_bfloat16 tmp[4];
#pragma unroll
            for (int r = 0; r < 4; ++r)
                tmp[r] = __float2bfloat16(acc[ft][et][r] + bv[r]);
            *(short4v*)(Y + (size_t)e * F + feat) = *(const short4v*)tmp;
        }
    }
}

// ---------------- merged dual MLP v3: register-resident hidden -------------
// 512 threads = 8 waves; each wave owns 16 rows x ALL 128 features
// (acc[8] = 32 regs, same pressure). The hidden layer never leaves the wave:
// layer-2 B fragments are built by intra-wave shuffles (hshuffle), removing
// the hid LDS buffer and its barriers. The freed LDS double-buffers the
// weights (2x32KB, still 2 blocks/CU): staging writes target the idle
// buffer, so only ONE barrier per layer boundary (4 total vs 7).
// Q2e may alias Xe (block reads its X rows at prologue, writes Q2 last).
__global__ __launch_bounds__(512, 4) void dual_mlp3_kernel(
    const __hip_bfloat16* Xe,
    const __hip_bfloat16* __restrict__ W1a_e, const float* __restrict__ b1a_e,
    const __hip_bfloat16* __restrict__ W2a_e, const float* __restrict__ b2a_e,
    const __hip_bfloat16* __restrict__ W1b_e, const float* __restrict__ b1b_e,
    const __hip_bfloat16* __restrict__ W2b_e, const float* __restrict__ b2b_e,
    __hip_bfloat16* __restrict__ Q1e, __hip_bfloat16* Q2e, int ntile_e,
    const __hip_bfloat16* __restrict__ Xn,
    const __hip_bfloat16* __restrict__ W1a_n,
    const __hip_bfloat16* __restrict__ W2a_n,
    const __hip_bfloat16* __restrict__ W1b_n, const float* __restrict__ b1b_n,
    const __hip_bfloat16* __restrict__ W2b_n, const float* __restrict__ b2b_n,
    __hip_bfloat16* __restrict__ Q1n, float* __restrict__ Q2n)
{
    __shared__ __hip_bfloat16 wbuf0[32 * 512];   // 32KB
    __shared__ __hip_bfloat16 wbuf1[32 * 512];   // 32KB
    const bool nn = (int)blockIdx.x >= ntile_e;   // node instance?
    const int tile = nn ? ((int)blockIdx.x - ntile_e) : (int)blockIdx.x;
    const __hip_bfloat16* X   = nn ? Xn : Xe;
    const __hip_bfloat16* W1a = nn ? W1a_n : W1a_e;
    const __hip_bfloat16* W2a = nn ? W2a_n : W2a_e;
    const __hip_bfloat16* W1b = nn ? W1b_n : W1b_e;
    const __hip_bfloat16* W2b = nn ? W2b_n : W2b_e;
    const float* b1a = nn ? nullptr : b1a_e;
    const float* b2a = nn ? nullptr : b2a_e;
    const float* b1b = nn ? b1b_n : b1b_e;
    const float* b2b = nn ? b2b_n : b2b_e;

    const int t = threadIdx.x;
    const int wave = t >> 6;       // 0..7, owns 16 rows
    const int lane = t & 63;
    const int quad = lane >> 4;
    const int l16  = lane & 15;
    const int row  = tile * 128 + wave * 16 + l16;

    // X fragments for this wave's 16 rows (4 ks x 16B = 16 VGPR)
    short8 bxk[4];
#pragma unroll
    for (int ks = 0; ks < 4; ++ks)
        bxk[ks] = *(const short8*)(X + (size_t)row * F + ks * 32 + quad * 8);

    short8 wreg[4];
    floatx4 acc[8];
    uint2 hpk[8];

    stage_issue(W1a, t, wreg);
    stage_write_frag(wbuf0, t, wreg);
    __syncthreads();

    // ===== layer A1 (read wbuf0) =====
    stage_issue(W2a, t, wreg);
    __builtin_amdgcn_sched_barrier(0);
#pragma unroll
    for (int ft = 0; ft < 8; ++ft) acc[ft] = (floatx4){0.f, 0.f, 0.f, 0.f};
#pragma unroll
    for (int ks = 0; ks < 4; ++ks) {
        short8 aw[8];
#pragma unroll
        for (int ft = 0; ft < 8; ++ft)
            aw[ft] = *(const short8*)(wbuf0 + (ft * 4 + ks) * 512
                                      + ((lane ^ (ks << 1)) * 8));
#pragma unroll
        for (int ft = 0; ft < 8; ++ft)
            acc[ft] = __builtin_amdgcn_mfma_f32_16x16x32_bf16(
                aw[ft], bxk[ks], acc[ft], 0, 0, 0);
    }
#pragma unroll
    for (int ft = 0; ft < 8; ++ft) {
        const int feat = ft * 16 + quad * 4;
        floatx4 bv = (floatx4){0.f, 0.f, 0.f, 0.f};
        if (b1a) bv = *(const floatx4*)(b1a + feat);
        const float v0 = silu_f(acc[ft][0] + bv[0]);
        const float v1 = silu_f(acc[ft][1] + bv[1]);
        const float v2 = silu_f(acc[ft][2] + bv[2]);
        const float v3 = silu_f(acc[ft][3] + bv[3]);
        hpk[ft] = make_uint2(pack_bf2(v0, v1), pack_bf2(v2, v3));
    }
    stage_write_frag(wbuf1, t, wreg);   // W2a -> idle buffer (no read conflict)
    __syncthreads();                    // all waves: A1 reads done, wbuf1 ready

    // ===== layer A2 (read wbuf1) =====
    stage_issue(W1b, t, wreg);
    __builtin_amdgcn_sched_barrier(0);
#pragma unroll
    for (int ft = 0; ft < 8; ++ft) acc[ft] = (floatx4){0.f, 0.f, 0.f, 0.f};
#pragma unroll
    for (int ks = 0; ks < 4; ++ks) {
        const short8 bh = hshuffle(hpk[2 * ks], hpk[2 * ks + 1], quad, l16);
        short8 aw[8];
#pragma unroll
        for (int ft = 0; ft < 8; ++ft)
            aw[ft] = *(const short8*)(wbuf1 + (ft * 4 + ks) * 512
                                      + ((lane ^ (ks << 1)) * 8));
#pragma unroll
        for (int ft = 0; ft < 8; ++ft)
            acc[ft] = __builtin_amdgcn_mfma_f32_16x16x32_bf16(
                aw[ft], bh, acc[ft], 0, 0, 0);
    }
#pragma unroll
    for (int ft = 0; ft < 8; ++ft) {
        const int feat = ft * 16 + quad * 4;
        floatx4 bv = (floatx4){0.f, 0.f, 0.f, 0.f};
        if (b2a) bv = *(const floatx4*)(b2a + feat);
        __align__(8) __hip_bfloat16 tmp[4];
#pragma unroll
        for (int r = 0; r < 4; ++r)
            tmp[r] = __float2bfloat16(acc[ft][r] + bv[r]);
        *(short4v*)((nn ? Q1n : Q1e) + (size_t)row * F + feat) = *(const short4v*)tmp;
    }
    stage_write_frag(wbuf0, t, wreg);   // W1b -> idle buffer
    __syncthreads();

    // ===== layer B1 (read wbuf0), reusing bxk =====
    stage_issue(W2b, t, wreg);
    __builtin_amdgcn_sched_barrier(0);
#pragma unroll
    for (int ft = 0; ft < 8; ++ft) acc[ft] = (floatx4){0.f, 0.f, 0.f, 0.f};
#pragma unroll
    for (int ks = 0; ks < 4; ++ks) {
        short8 aw[8];
#pragma unroll
        for (int ft = 0; ft < 8; ++ft)
            aw[ft] = *(const short8*)(wbuf0 + (ft * 4 + ks) * 512
                                      + ((lane ^ (ks << 1)) * 8));
#pragma unroll
        for (int ft = 0; ft < 8; ++ft)
            acc[ft] = __builtin_amdgcn_mfma_f32_16x16x32_bf16(
                aw[ft], bxk[ks], acc[ft], 0, 0, 0);
    }
#pragma unroll
    for (int ft = 0; ft < 8; ++ft) {
        const int feat = ft * 16 + quad * 4;
        floatx4 bv = (floatx4){0.f, 0.f, 0.f, 0.f};
        if (b1b) bv = *(const floatx4*)(b1b + feat);
        const float v0 = silu_f(acc[ft][0] + bv[0]);
        const float v1 = silu_f(acc[ft][1] + bv[1]);
        const float v2 = silu_f(acc[ft][2] + bv[2]);
        const float v3 = silu_f(acc[ft][3] + bv[3]);
        hpk[ft] = make_uint2(pack_bf2(v0, v1), pack_bf2(v2, v3));
    }
    stage_write_frag(wbuf1, t, wreg);   // W2b -> idle buffer
    __syncthreads();

    // ===== layer B2 (read wbuf1) =====
#pragma unroll
    for (int ft = 0; ft < 8; ++ft) acc[ft] = (floatx4){0.f, 0.f, 0.f, 0.f};
#pragma unroll
    for (int ks = 0; ks < 4; ++ks) {
        const short8 bh = hshuffle(hpk[2 * ks], hpk[2 * ks + 1], quad, l16);
        short8 aw[8];
#pragma unroll
        for (int ft = 0; ft < 8; ++ft)
            aw[ft] = *(const short8*)(wbuf1 + (ft * 4 + ks) * 512
                                      + ((lane ^ (ks << 1)) * 8));
#pragma unroll
        for (int ft = 0; ft < 8; ++ft)
            acc[ft] = __builtin_amdgcn_mfma_f32_16x16x32_bf16(
                aw[ft], bh, acc[ft], 0, 0, 0);
    }
#pragma unroll
    for (int ft = 0; ft < 8; ++ft) {
        const int feat = ft * 16 + quad * 4;
        floatx4 bv = (floatx4){0.f, 0.f, 0.f, 0.f};
        if (b2b) bv = *(const floatx4*)(b2b + feat);
        if (!nn) {
            __align__(8) __hip_bfloat16 tmp[4];
#pragma unroll
            for (int r = 0; r < 4; ++r)
                tmp[r] = __float2bfloat16(acc[ft][r] + bv[r]);
            *(short4v*)(Q2e + (size_t)row * F + feat) = *(const short4v*)tmp;
        } else {
            floatx4 v;
#pragma unroll
            for (int r = 0; r < 4; ++r) v[r] = acc[ft][r] + bv[r];
            *(floatx4*)(Q2n + (size_t)row * F + feat) = v;
        }
    }
}

// ---------------- edge invariant message: LDS-staged h rows -----------------
__global__ __launch_bounds__(256) void edge_inv_mfma_kernel(
    const __hip_bfloat16* __restrict__ dist_p,
    const __hip_bfloat16* __restrict__ empWt,   // [128 feat][32 k]
    const float* __restrict__ emp_b, const __hip_bfloat16* __restrict__ h,
    const int* __restrict__ src_p, const int* __restrict__ dst_p,
    __hip_bfloat16* __restrict__ Xbf, int E)
{
    __shared__ __hip_bfloat16 hrows[256 * HROWS_STRIDE];
    __shared__ int ridx[256];
    const int t = threadIdx.x;
    const int wave = t >> 6;
    const int lane = t & 63;
    const int quad = lane >> 4;
    const int l16  = lane & 15;
    const int e0b = blockIdx.x * 128;
    const int e0 = e0b + wave * 32;

    {
        const int le = (t < 128) ? t : (t - 128);
        const int e = e0b + le;
        const int idx = (e < E) ? ((t < 128) ? src_p[e] : dst_p[e]) : 0;
        ridx[t] = idx;
    }
    __syncthreads();

#pragma unroll
    for (int i = 0; i < 16; ++i) {
        const int idx = i * 256 + t;
        const int r = idx >> 4, part = idx & 15;
        const short8 v = *(const short8*)(h + (size_t)ridx[r] * F + part * 8);
        const short4v lo = __builtin_shufflevector(v, v, 0, 1, 2, 3);
        const short4v hi = __builtin_shufflevector(v, v, 4, 5, 6, 7);
        *(short4v*)(hrows + (size_t)r * HROWS_STRIDE + part * 8)     = lo;
        *(short4v*)(hrows + (size_t)r * HROWS_STRIDE + part * 8 + 4) = hi;
    }

    short8 bx[2], aw[8];
#pragma unroll
    for (int et = 0; et < 2; ++et)
        bx[et] = *(const short8*)(dist_p + (size_t)(e0 + et * 16 + l16) * KP + quad * 8);
#pragma unroll
    for (int ft = 0; ft < 8; ++ft)
        aw[ft] = *(const short8*)(empWt + (size_t)(ft * 16 + l16) * KP + quad * 8);

    floatx4 acc[8][2];
#pragma unroll
    for (int ft = 0; ft < 8; ++ft)
#pragma unroll
        for (int et = 0; et < 2; ++et)
            acc[ft][et] = __builtin_amdgcn_mfma_f32_16x16x32_bf16(
                aw[ft], bx[et], (floatx4){0.f, 0.f, 0.f, 0.f}, 0, 0, 0);

    __syncthreads();   // hrows complete

    int eidx[2];
#pragma unroll
    for (int et = 0; et < 2; ++et) eidx[et] = e0 + et * 16 + l16;

#pragma unroll
    for (int ft = 0; ft < 8; ++ft) {
        const int feat = ft * 16 + quad * 4;
        const floatx4 bv = *(const floatx4*)(emp_b + feat);
#pragma unroll
        for (int et = 0; et < 2; ++et) {
            const int le = wave * 32 + et * 16 + l16;      // local edge 0..127
            const short4v hs = *(const short4v*)(hrows + (size_t)le * HROWS_STRIDE + feat);
            const short4v hd = *(const short4v*)(hrows + (size_t)(128 + le) * HROWS_STRIDE + feat);
            const bool v = eidx[et] < E;
            __align__(8) __hip_bfloat16 tmp[4];
#pragma unroll
            for (int r = 0; r < 4; ++r) {
                const float m = v ? (acc[ft][et][r] + bv[r]) * bfs2f(hs[r]) * bfs2f(hd[r])
                                  : 0.0f;
                tmp[r] = __float2bfloat16(m);
            }
            *(short4v*)(Xbf + (size_t)eidx[et] * F + feat) = *(const short4v*)tmp;
        }
    }
}

// ---------------- merged prep: weights + empW + atom cast/pad + zero -------
__global__ void prep_all_kernel(
    const float* __restrict__ W0, const float* __restrict__ W1,
    const float* __restrict__ W2, const float* __restrict__ W3,
    const float* __restrict__ W4, const float* __restrict__ W5,
    const float* __restrict__ W6, const float* __restrict__ W7,
    const float* __restrict__ W8, const float* __restrict__ W9,
    const float* __restrict__ emp_W, const float* __restrict__ atom_node,
    __hip_bfloat16* __restrict__ Wt, __hip_bfloat16* __restrict__ empWt,
    __hip_bfloat16* __restrict__ atom_bf, __hip_bfloat16* __restrict__ atom_new_bf,
    int* __restrict__ counts, int nF, int nPadTot, int N)
{
    const int WTOT = 10 * F * F;      // 163840
    const int ETOT = F * KP;          // 4096
    const int S2 = WTOT + ETOT;
    const int S3 = S2 + nPadTot;
    const int S4 = S3 + (nPadTot - nF);
    const int total = S4 + N;
    const int stride = gridDim.x * blockDim.x;
    for (int i = blockIdx.x * blockDim.x + threadIdx.x; i < total; i += stride) {
        if (i < WTOT) {
            const int w = i >> 14;
            const int idx = i & (F * F - 1);
            const int n = idx >> 7, k = idx & 127;
            const float* W = (w == 0) ? W0 : (w == 1) ? W1 : (w == 2) ? W2
                           : (w == 3) ? W3 : (w == 4) ? W4 : (w == 5) ? W5
                           : (w == 6) ? W6 : (w == 7) ? W7 : (w == 8) ? W8 : W9;
            Wt[i] = __float2bfloat16(W[k * F + n]);
        } else if (i < S2) {
            const int j = i - WTOT;
            const int n = j >> 5, k = j & (KP - 1);
            empWt[j] = __float2bfloat16(k < NB ? emp_W[k * F + n] : 0.0f);
        } else if (i < S3) {
            const int j = i - S2;
            atom_bf[j] = __float2bfloat16(j < nF ? atom_node[j] : 0.0f);
        } else if (i < S4) {
            atom_new_bf[(i - S3) + nF] = __float2bfloat16(0.0f);
        } else {
            counts[i - S4] = 0;
        }
    }
}

// ---------------- CSR build (edges grouped by src) ----------------

__global__ void csr_count_kernel(const int* __restrict__ src,
                                 int* __restrict__ counts, int E) {
    const int stride = gridDim.x * blockDim.x;
    for (int e = blockIdx.x * blockDim.x + threadIdx.x; e < E; e += stride)
        atomicAdd(&counts[src[e]], 1);
}

__global__ __launch_bounds__(1024) void csr_scan_kernel(
    const int* __restrict__ counts, int* __restrict__ offsets,
    int* __restrict__ cursor, int N)
{
    constexpr int T = 1024;
    const int t = threadIdx.x;
    const int per = (N + T - 1) / T;
    const int base = t * per;
    int lsum = 0;
    for (int i = 0; i < per; ++i) {
        int idx = base + i;
        if (idx < N) lsum += counts[idx];
    }
    __shared__ int s[T];
    s[t] = lsum;
    __syncthreads();
    for (int off = 1; off < T; off <<= 1) {
        int v = (t >= off) ? s[t - off] : 0;
        __syncthreads();
        s[t] += v;
        __syncthreads();
    }
    int run = s[t] - lsum;
    for (int i = 0; i < per; ++i) {
        int idx = base + i;
        if (idx < N) {
            offsets[idx] = run;
            cursor[idx] = run;
            run += counts[idx];
        }
    }
    if (t == T - 1) offsets[N] = run;
}

__global__ void csr_perm_kernel(const int* __restrict__ src,
                                const int* __restrict__ dst,
                                const float* __restrict__ disp_edge,
                                const float* __restrict__ dist_edge,
                                int* __restrict__ cursor,
                                int* __restrict__ src_p,
                                int* __restrict__ dst_p,
                                float* __restrict__ de_p,
                                __hip_bfloat16* __restrict__ dist_p, int E) {
    const int stride = gridDim.x * blockDim.x;
    for (int e = blockIdx.x * blockDim.x + threadIdx.x; e < E; e += stride) {
        const int s = src[e];
        const int pos = atomicAdd(&cursor[s], 1);
        src_p[pos] = s;
        dst_p[pos] = dst[e];
        de_p[3 * pos + 0] = disp_edge[3 * e + 0];
        de_p[3 * pos + 1] = disp_edge[3 * e + 1];
        de_p[3 * pos + 2] = disp_edge[3 * e + 2];
        __align__(16) __hip_bfloat16 tmp[KP];
#pragma unroll
        for (int k = 0; k < KP; ++k)
            tmp[k] = __float2bfloat16(k < NB ? dist_edge[(size_t)e * NB + k] : 0.0f);
#pragma unroll
        for (int q = 0; q < 4; ++q)
            *(short8*)(dist_p + (size_t)pos * KP + q * 8) = ((const short8*)tmp)[q];
    }
}

// ---------- per-node gathers: wave-per-node, 2 features/lane (4B+ loads) ----

__global__ __launch_bounds__(256) void gather_inv_kernel(
    const __hip_bfloat16* __restrict__ inv_msg, const int* __restrict__ offsets,
    const float* __restrict__ atom,
    float* __restrict__ atom_new, __hip_bfloat16* __restrict__ atom_new_bf, int N)
{
    const int n = blockIdx.x * 4 + (threadIdx.x >> 6);
    if (n >= N) return;
    const int f0 = (threadIdx.x & 63) * 2;
    const int p0 = offsets[n], p1 = offsets[n + 1];
    float a0 = 0.0f, a1 = 0.0f;
    for (int p = p0; p < p1; ++p) {
        const unsigned int u = *(const unsigned int*)(inv_msg + (size_t)p * F + f0);
        a0 += lo_bf(u);
        a1 += hi_bf(u);
    }
    const float2 av = *(const float2*)(atom + (size_t)n * F + f0);
    const float v0 = av.x + a0, v1 = av.y + a1;
    *(float2*)(atom_new + (size_t)n * F + f0) = make_float2(v0, v1);
    __hip_bfloat16 b0 = __float2bfloat16(v0), b1 = __float2bfloat16(v1);
    *(ushort2*)(atom_new_bf + (size_t)n * F + f0) =
        make_ushort2(*(unsigned short*)&b0, *(unsigned short*)&b1);
}

// eq1 gather + out_force + packed {bf16(disp_node), bf16(eq3i*agg1)} table
__global__ __launch_bounds__(256) void gather_eq1_kernel(
    const __hip_bfloat16* __restrict__ eqm, const float* __restrict__ de_p,
    const int* __restrict__ offsets,
    const float* __restrict__ force, const float* __restrict__ disp_node,
    const __hip_bfloat16* __restrict__ eq3i_bf,
    float* __restrict__ out_force, ushort2* __restrict__ pk, int N)
{
    const int n = blockIdx.x * 4 + (threadIdx.x >> 6);
    if (n >= N) return;
    const int f0 = (threadIdx.x & 63) * 2;
    const int p0 = offsets[n], p1 = offsets[n + 1];
    float a00 = 0.f, a01 = 0.f, a10 = 0.f, a11 = 0.f, a20 = 0.f, a21 = 0.f;
    for (int p = p0; p < p1; ++p) {
        const unsigned int u = *(const unsigned int*)(eqm + (size_t)p * F + f0);
        const float m0 = lo_bf(u), m1 = hi_bf(u);
        const float d0 = de_p[(size_t)p * 3 + 0];
        const float d1 = de_p[(size_t)p * 3 + 1];
        const float d2 = de_p[(size_t)p * 3 + 2];
        a00 = fmaf(m0, d0, a00); a01 = fmaf(m1, d0, a01);
        a10 = fmaf(m0, d1, a10); a11 = fmaf(m1, d1, a11);
        a20 = fmaf(m0, d2, a20); a21 = fmaf(m1, d2, a21);
    }
    const unsigned int ug = *(const unsigned int*)(eq3i_bf + (size_t)n * F + f0);
    const float g0 = lo_bf(ug), g1 = hi_bf(ug);
    const size_t b = (size_t)n * 3 * F + f0;

    float2 f;
    f = *(const float2*)(force + b);
    *(float2*)(out_force + b) = make_float2(f.x + a00, f.y + a01);
    f = *(const float2*)(force + b + F);
    *(float2*)(out_force + b + F) = make_float2(f.x + a10, f.y + a11);
    f = *(const float2*)(force + b + 2 * F);
    *(float2*)(out_force + b + 2 * F) = make_float2(f.x + a20, f.y + a21);

    float2 dn;
    dn = *(const float2*)(disp_node + b);
    *(uint2*)(pk + b) = make_uint2(pack_bf2(dn.x, g0 * a00), pack_bf2(dn.y, g1 * a01));
    dn = *(const float2*)(disp_node + b + F);
    *(uint2*)(pk + b + F) = make_uint2(pack_bf2(dn.x, g0 * a10), pack_bf2(dn.y, g1 * a11));
    dn = *(const float2*)(disp_node + b + 2 * F);
    *(uint2*)(pk + b + 2 * F) = make_uint2(pack_bf2(dn.x, g0 * a20), pack_bf2(dn.y, g1 * a21));
}

// merged eq2+eq3 gather + final update + LayerNorm
__global__ __launch_bounds__(256) void gather_eq23_ln_kernel(
    const __hip_bfloat16* __restrict__ eqm2, const ushort2* __restrict__ pk,
    const float* __restrict__ disp_node,
    const int* __restrict__ dst_p, const int* __restrict__ offsets,
    const float* __restrict__ atom_new, const float* __restrict__ upd,
    const float* __restrict__ out_force,
    const float* __restrict__ ln_g, const float* __restrict__ ln_b,
    float* __restrict__ out_disp, float* __restrict__ out_atom, int N)
{
    const int n = blockIdx.x * 4 + (threadIdx.x >> 6);
    if (n >= N) return;
    const int f0 = (threadIdx.x & 63) * 2;
    const int p0 = offsets[n], p1 = offsets[n + 1];
    float a00 = 0.f, a01 = 0.f, a10 = 0.f, a11 = 0.f, a20 = 0.f, a21 = 0.f;
    int d = (p0 < p1) ? dst_p[p0] : 0;
    for (int p = p0; p < p1; ++p) {
        const int dn = (p + 1 < p1) ? dst_p[p + 1] : 0;
        const unsigned int u = *(const unsigned int*)(eqm2 + (size_t)p * F + f0);
        const float m0 = lo_bf(u), m1 = hi_bf(u);
        const size_t pb = (size_t)d * 3 * F + f0;
        const uint2 c0 = *(const uint2*)(pk + pb);
        const uint2 c1 = *(const uint2*)(pk + pb + F);
        const uint2 c2 = *(const uint2*)(pk + pb + 2 * F);
        a00 += m0 * lo_bf(c0.x) + hi_bf(c0.x);
        a01 += m1 * lo_bf(c0.y) + hi_bf(c0.y);
        a10 += m0 * lo_bf(c1.x) + hi_bf(c1.x);
        a11 += m1 * lo_bf(c1.y) + hi_bf(c1.y);
        a20 += m0 * lo_bf(c2.x) + hi_bf(c2.x);
        a21 += m1 * lo_bf(c2.y) + hi_bf(c2.y);
        d = dn;
    }
    const size_t b = (size_t)n * 3 * F + f0;
    float2 dn2;
    dn2 = *(const float2*)(disp_node + b);
    const float2 od0 = make_float2(dn2.x + a00, dn2.y + a01);
    dn2 = *(const float2*)(disp_node + b + F);
    const float2 od1 = make_float2(dn2.x + a10, dn2.y + a11);
    dn2 = *(const float2*)(disp_node + b + 2 * F);
    const float2 od2 = make_float2(dn2.x + a20, dn2.y + a21);
    *(float2*)(out_disp + b)         = od0;
    *(float2*)(out_disp + b + F)     = od1;
    *(float2*)(out_disp + b + 2 * F) = od2;

    const float2 fo0 = *(const float2*)(out_force + b);
    const float2 fo1 = *(const float2*)(out_force + b + F);
    const float2 fo2 = *(const float2*)(out_force + b + 2 * F);
    const float s0 = -(fo0.x * od0.x + fo1.x * od1.x + fo2.x * od2.x);
    const float s1 = -(fo0.y * od0.y + fo1.y * od1.y + fo2.y * od2.y);

    const float2 an = *(const float2*)(atom_new + (size_t)n * F + f0);
    const float2 up = *(const float2*)(upd + (size_t)n * F + f0);
    const float y0 = an.x + up.x * s0;
    const float y1 = an.y + up.y * s1;

    float sy = y0 + y1, syy = y0 * y0 + y1 * y1;
#pragma unroll
    for (int m = 1; m < 64; m <<= 1) {
        sy  += __shfl_xor(sy, m);
        syy += __shfl_xor(syy, m);
    }
    const float mu = sy * (1.0f / F);
    float var = syy * (1.0f / F) - mu * mu;
    if (var < 0.0f) var = 0.0f;
    const float rstd = rsqrtf(var + 1e-5f);

    const float2 gg = *(const float2*)(ln_g + f0);
    const float2 bb = *(const float2*)(ln_b + f0);
    *(float2*)(out_atom + (size_t)n * F + f0) =
        make_float2((y0 - mu) * rstd * gg.x + bb.x,
                    (y1 - mu) * rstd * gg.y + bb.y);
}

extern "C" void kernel_launch(void* const* d_in, const int* in_sizes, int n_in,
                              void* d_out, int out_size, void* d_ws, size_t ws_size,
                              hipStream_t stream)
{
    const float* atom_node  = (const float*)d_in[0];
    const float* force_node = (const float*)d_in[1];
    const float* disp_node  = (const float*)d_in[2];
    const float* disp_edge  = (const float*)d_in[3];
    const float* dist_edge  = (const float*)d_in[4];
    const int*   edge_index = (const int*)d_in[5];
    const float* nmp_W1 = (const float*)d_in[6];
    const float* nmp_b1 = (const float*)d_in[7];
    const float* nmp_W2 = (const float*)d_in[8];
    const float* nmp_b2 = (const float*)d_in[9];
    const float* emp_W  = (const float*)d_in[10];
    const float* emp_b  = (const float*)d_in[11];
    const float* eq1_W1 = (const float*)d_in[12];
    const float* eq1_b1 = (const float*)d_in[13];
    const float* eq1_W2 = (const float*)d_in[14];
    const float* eq1_b2 = (const float*)d_in[15];
    const float* eq2_W1 = (const float*)d_in[16];
    const float* eq2_b1 = (const float*)d_in[17];
    const float* eq2_W2 = (const float*)d_in[18];
    const float* eq2_b2 = (const float*)d_in[19];
    const float* eq3_W1 = (const float*)d_in[20];
    const float* eq3_W2 = (const float*)d_in[21];
    const float* upd_W1 = (const float*)d_in[22];
    const float* upd_b1 = (const float*)d_in[23];
    const float* upd_W2 = (const float*)d_in[24];
    const float* upd_b2 = (const float*)d_in[25];
    const float* ln_g   = (const float*)d_in[26];
    const float* ln_b   = (const float*)d_in[27];

    const int N = in_sizes[0] / F;            // 10000
    const int E = in_sizes[4] / NB;           // 200000
    const int Mp  = ((E + 127) / 128) * 128;  // 200064
    const int Mp2 = ((N + 127) / 128) * 128;  // 10112
    const int* src = edge_index;
    const int* dst = edge_index + E;
    const int nF = N * F, n3F = N * 3 * F;

    float* out_atom  = (float*)d_out;
    float* out_force = out_atom + (size_t)nF;
    float* out_disp  = out_force + (size_t)n3F;

    // ---- workspace layout ----
    char* p = (char*)d_ws;
    int* counts  = (int*)p;
    int* offsets = counts + N;
    int* cursor  = offsets + (N + 1);
    int* src_p   = cursor + N;
    int* dst_p   = src_p + E;
    size_t off = (size_t)(3 * N + 1 + 2 * E) * sizeof(int);
    off = (off + 63) & ~(size_t)63;
    float* de_p = (float*)(p + off); off += (size_t)3 * E * sizeof(float);
    off = (off + 63) & ~(size_t)63;
    __hip_bfloat16* dist_p = (__hip_bfloat16*)(p + off); off += (size_t)Mp * KP * 2;
    __hip_bfloat16* empWt  = (__hip_bfloat16*)(p + off); off += (size_t)F * KP * 2;

    __hip_bfloat16* h_bf        = (__hip_bfloat16*)(p + off); off += (size_t)Mp2 * F * 2;
    __hip_bfloat16* atom_bf     = (__hip_bfloat16*)(p + off); off += (size_t)Mp2 * F * 2;
    __hip_bfloat16* atom_new_bf = (__hip_bfloat16*)(p + off); off += (size_t)Mp2 * F * 2;
    __hip_bfloat16* eq3i_bf     = (__hip_bfloat16*)(p + off); off += (size_t)Mp2 * F * 2;
    off = (off + 63) & ~(size_t)63;
    float* atom_new = (float*)(p + off); off += (size_t)nF * 4;
    float* upd_f    = (float*)(p + off); off += (size_t)Mp2 * F * 4;
    ushort2* pk     = (ushort2*)(p + off); off += (size_t)n3F * sizeof(ushort2);
    off = (off + 63) & ~(size_t)63;
    __hip_bfloat16* Xbf = (__hip_bfloat16*)(p + off); off += (size_t)Mp * F * 2;
    __hip_bfloat16* Q1  = (__hip_bfloat16*)(p + off); off += (size_t)Mp * F * 2;
    __hip_bfloat16* Q2  = Xbf;   // alias: edge blocks read their X rows before writing Q2 rows
    __hip_bfloat16* Wt  = (__hip_bfloat16*)(p + off); // 10*F*F bf16
    __hip_bfloat16* Wt_eq1a = Wt + 0 * F * F;
    __hip_bfloat16* Wt_eq1b = Wt + 1 * F * F;
    __hip_bfloat16* Wt_eq2a = Wt + 2 * F * F;
    __hip_bfloat16* Wt_eq2b = Wt + 3 * F * F;
    __hip_bfloat16* Wt_nmpa = Wt + 4 * F * F;
    __hip_bfloat16* Wt_nmpb = Wt + 5 * F * F;
    __hip_bfloat16* Wt_eq3a = Wt + 6 * F * F;
    __hip_bfloat16* Wt_eq3b = Wt + 7 * F * F;
    __hip_bfloat16* Wt_upda = Wt + 8 * F * F;
    __hip_bfloat16* Wt_updb = Wt + 9 * F * F;

    // ---- merged prep (weights + empW + atom cast/pad + atom_new pad + zero counts)
    prep_all_kernel<<<1024, 256, 0, stream>>>(
        eq1_W1, eq1_W2, eq2_W1, eq2_W2, nmp_W1, nmp_W2, eq3_W1, eq3_W2,
        upd_W1, upd_W2, emp_W, atom_node,
        Wt, empWt, atom_bf, atom_new_bf, counts, nF, Mp2 * F, N);

    // ---- CSR build ----
    csr_count_kernel<<<256, 256, 0, stream>>>(src, counts, E);
    csr_scan_kernel<<<1, 1024, 0, stream>>>(counts, offsets, cursor, N);
    csr_perm_kernel<<<256, 256, 0, stream>>>(src, dst, disp_edge, dist_edge,
                                             cursor, src_p, dst_p, de_p, dist_p, E);

    // ---- h = mlp2(atom_node, nmp), LDS-staged weights ----
    mlp_staged_kernel<<<Mp2 / 128, 512, 0, stream>>>(
        atom_bf, Wt_nmpa, nmp_b1, Wt_nmpb, nmp_b2, h_bf);

    // ---- invariant message (MFMA + LDS-staged h products) + node aggregation
    edge_inv_mfma_kernel<<<Mp / 128, 256, 0, stream>>>(
        dist_p, empWt, emp_b, h_bf, src_p, dst_p, Xbf, E);
    gather_inv_kernel<<<(N + 3) / 4, 256, 0, stream>>>(Xbf, offsets, atom_node,
                                                       atom_new, atom_new_bf, N);

    // ---- merged dual MLPs v3: edge eq1+eq2 (1563 tiles) + node eq3+upd (79)
    {
        const int ntileE = Mp / 128;
        const int ntileN = Mp2 / 128;
        dual_mlp3_kernel<<<ntileE + ntileN, 512, 0, stream>>>(
            Xbf, Wt_eq1a, eq1_b1, Wt_eq1b, eq1_b2,
            Wt_eq2a, eq2_b1, Wt_eq2b, eq2_b2, Q1, Q2, ntileE,
            atom_new_bf, Wt_eq3a, Wt_eq3b,
            Wt_upda, upd_b1, Wt_updb, upd_b2, eq3i_bf, upd_f);
    }

    // ---- gathers (+ fused LN in eq23) ----
    gather_eq1_kernel<<<(N + 3) / 4, 256, 0, stream>>>(
        Q1, de_p, offsets, force_node, disp_node, eq3i_bf, out_force, pk, N);
    gather_eq23_ln_kernel<<<(N + 3) / 4, 256, 0, stream>>>(
        Q2, pk, disp_node, dst_p, offsets, atom_new, upd_f, out_force,
        ln_g, ln_b, out_disp, out_atom, N);
}